// Round 7
// baseline (1296.588 us; speedup 1.0000x reference)
//
#include <hip/hip_runtime.h>

#define S_TOT   10548
#define M_ROWS  21096
#define M_PAD   21120          // 330*64 = 660*32
#define E_DIM   256
#define NH_DIM  8
#define HD_DIM  32
#define DF_DIM  1024
#define NLAYERS 6

typedef unsigned short ushort_t;
typedef __attribute__((ext_vector_type(8))) short bf16x8;
typedef __attribute__((ext_vector_type(4))) float f32x4;

__device__ inline ushort_t f2bf(float f) {
    unsigned u = __float_as_uint(f);
    u += 0x7FFF + ((u >> 16) & 1);          // RNE
    return (ushort_t)(u >> 16);
}
__device__ inline float bf2f(ushort_t h) {
    return __uint_as_float(((unsigned)h) << 16);
}
__device__ inline f32x4 up2(unsigned a, unsigned b) {
    f32x4 v;
    v.x = __uint_as_float(a << 16);
    v.y = __uint_as_float(a & 0xffff0000u);
    v.z = __uint_as_float(b << 16);
    v.w = __uint_as_float(b & 0xffff0000u);
    return v;
}
// async global->LDS, 16B per lane; LDS dest wave-uniform, lane scatters at
// dest + lane*16.
__device__ inline void gload16(const ushort_t* g, ushort_t* l) {
    __builtin_amdgcn_global_load_lds(
        (const __attribute__((address_space(1))) void*)g,
        (__attribute__((address_space(3))) void*)l, 16, 0, 0);
}

// ---------------------------------------------------------------------------
// Input assembly v2: LDS-transpose tiles, both sides coalesced.
// grid = (331 j-tiles, 8 e-tiles, 2 batches).
// ---------------------------------------------------------------------------
__global__ __launch_bounds__(256)
void assemble_kernel(const float* __restrict__ f0, const float* __restrict__ p0,
                     const float* __restrict__ f1, const float* __restrict__ p1,
                     const float* __restrict__ f2, const float* __restrict__ p2,
                     const float* __restrict__ f3, const float* __restrict__ p3,
                     const float* __restrict__ lemb,
                     float* __restrict__ x, ushort_t* __restrict__ posb,
                     ushort_t* __restrict__ xb, ushort_t* __restrict__ qb)
{
    __shared__ float tf[32][33];
    __shared__ float tp[32][33];

    int tb = blockIdx.x;
    int e0 = blockIdx.y * 32;
    int b  = blockIdx.z;
    int lvl, j0, n, s0; const float* f; const float* p;
    if (tb < 288)      { lvl = 0; j0 = tb * 32;         n = 9216; s0 = 0;     f = f0; p = p0; }
    else if (tb < 324) { lvl = 1; j0 = (tb - 288) * 32; n = 1152; s0 = 9216;  f = f1; p = p1; }
    else if (tb < 329) { lvl = 2; j0 = (tb - 324) * 32; n = 144;  s0 = 10368; f = f2; p = p2; }
    else               { lvl = 3; j0 = (tb - 329) * 32; n = 36;   s0 = 10512; f = f3; p = p3; }

    int tx = threadIdx.x & 31, ty = threadIdx.x >> 5;
    bool jv = (j0 + tx) < n;
    size_t base = (size_t)(b * E_DIM + e0) * n + j0 + tx;
    #pragma unroll
    for (int i = 0; i < 4; ++i) {
        int e = ty + i * 8;
        float fv = 0.f, pv = 0.f;
        if (jv) {
            fv = f[base + (size_t)e * n];
            pv = p[base + (size_t)e * n];
        }
        tf[e][tx] = fv;
        tp[e][tx] = pv;
    }
    __syncthreads();

    float lv = lemb[lvl * E_DIM + e0 + tx];
    #pragma unroll
    for (int i = 0; i < 4; ++i) {
        int jl = ty + i * 8;
        if (j0 + jl < n) {
            int r = b * S_TOT + s0 + j0 + jl;
            float xv = tf[tx][jl];
            float pv = tp[tx][jl] + lv;
            size_t o = (size_t)r * E_DIM + e0 + tx;
            x[o]    = xv;
            posb[o] = f2bf(pv);
            xb[o]   = f2bf(xv);
            qb[o]   = f2bf(xv + pv);
        }
    }
}

// ---------------------------------------------------------------------------
// Weight convert+transpose: src f32 [L,K,N] -> dst bf16 [L(stride), rowOff+N, K]
// ---------------------------------------------------------------------------
__global__ __launch_bounds__(256)
void transpose_cvt_kernel(const float* __restrict__ src, ushort_t* __restrict__ dst,
                          int K, int N, int dstLayerStride, int dstRowOff)
{
    __shared__ float tile[32][33];
    int l  = blockIdx.z;
    int n0 = blockIdx.x * 32, k0 = blockIdx.y * 32;
    int tx = threadIdx.x & 31, ty = threadIdx.x >> 5;
    const float* s = src + (size_t)l * K * N;
    ushort_t* d    = dst + (size_t)l * dstLayerStride + (size_t)dstRowOff * K;
    #pragma unroll
    for (int i = 0; i < 32; i += 8)
        tile[ty + i][tx] = s[(size_t)(k0 + ty + i) * N + n0 + tx];
    __syncthreads();
    #pragma unroll
    for (int i = 0; i < 32; i += 8)
        d[(size_t)(n0 + ty + i) * K + k0 + tx] = f2bf(tile[tx][ty + i]);
}

// ---------------------------------------------------------------------------
// 64x256-tile bf16 MFMA GEMM (part1), double-buffered single-sync K-loop.
// grid.x=sup: 0=value (A=xb, permute store), 1=off[0:256),
// 2=off[256:384)+attn (A=qb); off/attn stored HEAD-MAJOR.
// ---------------------------------------------------------------------------
__global__ __launch_bounds__(256, 2)
void gemm_part1(const ushort_t* __restrict__ A0, const ushort_t* __restrict__ A1,
                const ushort_t* __restrict__ BtBase,
                const float* __restrict__ b1, const float* __restrict__ b2,
                const float* __restrict__ b3,
                ushort_t* __restrict__ O1, ushort_t* __restrict__ O2,
                ushort_t* __restrict__ O3, int M)
{
    __shared__ short As[2][64 * 32];
    __shared__ short Bs[2][256 * 32];
    const int K = 256;
    int t    = threadIdx.x;
    int sup  = blockIdx.x;
    int row0 = blockIdx.y * 64;
    int lane = t & 63;
    int w    = t >> 6;
    int wn   = w * 64;
    const int quad = lane >> 4, lrow = lane & 15;

    const ushort_t* A  = (sup != 0) ? A1 : A0;
    const ushort_t* Bt = BtBase + (size_t)sup * 256 * K;

    f32x4 acc[4][4];
    #pragma unroll
    for (int i = 0; i < 4; ++i)
        #pragma unroll
        for (int j = 0; j < 4; ++j)
            acc[i][j] = (f32x4){0.f, 0.f, 0.f, 0.f};

    int srow = lane >> 2;
    const int sw = (((lane & 3) ^ ((lane >> 3) & 3)) * 8);     // swizzled k-seg
    const int rs = ((quad ^ ((lrow >> 1) & 3)) * 8);           // fragment slot
    const ushort_t* Ag = A + (size_t)(row0 + w * 16 + srow) * K + sw;
    const ushort_t* Bg = Bt + (size_t)(w * 64 + srow) * K + sw;

    // prologue: stage k0=0 into buffer 0
    gload16(Ag, (ushort_t*)&As[0][(w * 16) * 32]);
    #pragma unroll
    for (int q = 0; q < 4; ++q)
        gload16(Bg + (size_t)(q * 16) * K,
                (ushort_t*)&Bs[0][(w * 64 + q * 16) * 32]);

    #pragma unroll
    for (int k0 = 0; k0 < K; k0 += 32) {
        const int cur = (k0 >> 5) & 1;
        __syncthreads();                      // stage(k) landed; buf cur^1 free
        if (k0 + 32 < K) {
            const int nxt = cur ^ 1;
            gload16(Ag + k0 + 32, (ushort_t*)&As[nxt][(w * 16) * 32]);
            #pragma unroll
            for (int q = 0; q < 4; ++q)
                gload16(Bg + (size_t)(q * 16) * K + k0 + 32,
                        (ushort_t*)&Bs[nxt][(w * 64 + q * 16) * 32]);
        }
        bf16x8 af[4], bfr[4];
        #pragma unroll
        for (int i = 0; i < 4; ++i)
            af[i] = *(const bf16x8*)&As[cur][(i * 16 + lrow) * 32 + rs];
        #pragma unroll
        for (int j = 0; j < 4; ++j)
            bfr[j] = *(const bf16x8*)&Bs[cur][(wn + j * 16 + lrow) * 32 + rs];
        #pragma unroll
        for (int i = 0; i < 4; ++i)
            #pragma unroll
            for (int j = 0; j < 4; ++j)
                acc[i][j] = __builtin_amdgcn_mfma_f32_16x16x32_bf16(af[i], bfr[j], acc[i][j], 0, 0, 0);
    }

    #pragma unroll
    for (int j = 0; j < 4; ++j) {
        int col = wn + j * 16 + lrow;     // 0..255 local
        float bia = (sup == 0) ? b1[col]
                  : (sup == 1) ? b2[col]
                  : (col < 128) ? b2[256 + col] : b3[col - 128];
        #pragma unroll
        for (int i = 0; i < 4; ++i)
            #pragma unroll
            for (int rg = 0; rg < 4; ++rg) {
                int row = row0 + i * 16 + quad * 4 + rg;
                if (row < M) {
                    float v = acc[i][j][rg] + bia;
                    if (sup == 0) {
                        int b = (row >= S_TOT) ? 1 : 0;
                        int s = row - b * S_TOT;
                        O1[(((size_t)(b * NH_DIM + (col >> 5))) * S_TOT + s) * HD_DIM + (col & 31)] = f2bf(v);
                    } else if (sup == 2 && col >= 128) {
                        int acol = col - 128;
                        O3[((size_t)(acol >> 4) * M_ROWS + row) * 16 + (acol & 15)] = f2bf(v);
                    } else {
                        int ocol = (sup == 1) ? col : 256 + col;
                        int hh = (ocol * 1366) >> 16;            // /48
                        O2[((size_t)hh * M_ROWS + row) * 48 + (ocol - hh * 48)] = f2bf(v);
                    }
                }
            }
    }
}

// ---------------------------------------------------------------------------
// 32x256-tile bf16 MFMA GEMM + FUSED residual + LayerNorm epilogue (out-proj).
// Double-buffered single-sync K-loop; red scratch aliased onto As[0].
// LDS 36KB -> 4 blocks/CU.
// ---------------------------------------------------------------------------
__global__ __launch_bounds__(256, 4)
void gemm_ln(const ushort_t* __restrict__ A, const ushort_t* __restrict__ Bt,
             const float* __restrict__ bias,
             float* __restrict__ x, ushort_t* __restrict__ xb,
             const float* __restrict__ lng, const float* __restrict__ lnb,
             int M)
{
    __shared__ short As[2][32 * 32];
    __shared__ short Bs[2][256 * 32];
    float* red1 = (float*)&As[0][0];          // 160 floats
    float* red2 = red1 + 32 * 5;              // 160 floats (1280B <= 2048B)
    const int K = 256;
    int t    = threadIdx.x;
    int row0 = blockIdx.x * 32;
    int lane = t & 63;
    int w    = t >> 6;
    int wn   = w * 64;
    const int quad = lane >> 4, lrow = lane & 15;

    f32x4 acc[2][4];
    #pragma unroll
    for (int i = 0; i < 2; ++i)
        #pragma unroll
        for (int j = 0; j < 4; ++j)
            acc[i][j] = (f32x4){0.f, 0.f, 0.f, 0.f};

    int srow = lane >> 2;
    const int sw = (((lane & 3) ^ ((lane >> 3) & 3)) * 8);
    const int rs = ((quad ^ ((lrow >> 1) & 3)) * 8);
    const ushort_t* Ag = A + (size_t)(row0 + w * 16 + srow) * K + sw;   // w<2
    const ushort_t* Bg = Bt + (size_t)(w * 64 + srow) * K + sw;

    if (w < 2) gload16(Ag, (ushort_t*)&As[0][(w * 16) * 32]);
    #pragma unroll
    for (int q = 0; q < 4; ++q)
        gload16(Bg + (size_t)(q * 16) * K,
                (ushort_t*)&Bs[0][(w * 64 + q * 16) * 32]);

    #pragma unroll
    for (int k0 = 0; k0 < K; k0 += 32) {
        const int cur = (k0 >> 5) & 1;
        __syncthreads();
        if (k0 + 32 < K) {
            const int nxt = cur ^ 1;
            if (w < 2) gload16(Ag + k0 + 32, (ushort_t*)&As[nxt][(w * 16) * 32]);
            #pragma unroll
            for (int q = 0; q < 4; ++q)
                gload16(Bg + (size_t)(q * 16) * K + k0 + 32,
                        (ushort_t*)&Bs[nxt][(w * 64 + q * 16) * 32]);
        }
        bf16x8 af[2], bfr[4];
        #pragma unroll
        for (int i = 0; i < 2; ++i)
            af[i] = *(const bf16x8*)&As[cur][(i * 16 + lrow) * 32 + rs];
        #pragma unroll
        for (int j = 0; j < 4; ++j)
            bfr[j] = *(const bf16x8*)&Bs[cur][(wn + j * 16 + lrow) * 32 + rs];
        #pragma unroll
        for (int i = 0; i < 2; ++i)
            #pragma unroll
            for (int j = 0; j < 4; ++j)
                acc[i][j] = __builtin_amdgcn_mfma_f32_16x16x32_bf16(af[i], bfr[j], acc[i][j], 0, 0, 0);
    }

    // ---- fused epilogue: v = x + (y + bias); LayerNorm per row ----
    float gj[4], bj[4], bi[4];
    #pragma unroll
    for (int j = 0; j < 4; ++j) {
        int col = wn + j * 16 + lrow;
        gj[j] = lng[col];
        bj[j] = lnb[col];
        bi[j] = bias[col];
    }

    #pragma unroll
    for (int i = 0; i < 2; ++i)
        #pragma unroll
        for (int rg = 0; rg < 4; ++rg) {
            int row = row0 + i * 16 + quad * 4 + rg;
            #pragma unroll
            for (int j = 0; j < 4; ++j) {
                int col = wn + j * 16 + lrow;
                float xres = (row < M) ? x[(size_t)row * 256 + col] : 0.f;
                acc[i][j][rg] += bi[j] + xres;
            }
            float p1 = acc[i][0][rg] + acc[i][1][rg] + acc[i][2][rg] + acc[i][3][rg];
            float p2 = acc[i][0][rg] * acc[i][0][rg] + acc[i][1][rg] * acc[i][1][rg]
                     + acc[i][2][rg] * acc[i][2][rg] + acc[i][3][rg] * acc[i][3][rg];
            p1 += __shfl_xor(p1, 1); p2 += __shfl_xor(p2, 1);
            p1 += __shfl_xor(p1, 2); p2 += __shfl_xor(p2, 2);
            p1 += __shfl_xor(p1, 4); p2 += __shfl_xor(p2, 4);
            p1 += __shfl_xor(p1, 8); p2 += __shfl_xor(p2, 8);
            if (lrow == 0) {
                int rl = i * 16 + quad * 4 + rg;
                red1[rl * 5 + w] = p1;
                red2[rl * 5 + w] = p2;
            }
        }
    __syncthreads();

    #pragma unroll
    for (int i = 0; i < 2; ++i)
        #pragma unroll
        for (int rg = 0; rg < 4; ++rg) {
            int rl = i * 16 + quad * 4 + rg;
            float S1 = red1[rl * 5 + 0] + red1[rl * 5 + 1] + red1[rl * 5 + 2] + red1[rl * 5 + 3];
            float S2 = red2[rl * 5 + 0] + red2[rl * 5 + 1] + red2[rl * 5 + 2] + red2[rl * 5 + 3];
            float mean = S1 * (1.f / 256);
            float rstd = rsqrtf(S2 * (1.f / 256) - mean * mean + 1e-5f);
            int row = row0 + rl;
            if (row < M) {
                #pragma unroll
                for (int j = 0; j < 4; ++j) {
                    int col = wn + j * 16 + lrow;
                    float out = (acc[i][j][rg] - mean) * rstd * gj[j] + bj[j];
                    size_t o = (size_t)row * 256 + col;
                    x[o]  = out;
                    xb[o] = f2bf(out);
                }
            }
        }
}

// ---------------------------------------------------------------------------
// FFN part 1: hidden = relu(xb @ W1 + b1), bf16 to global.
// 64x256 tile, grid (4 hidden-chunks, 330 row-tiles). Clone of gemm_part1
// loop. LDS 40KB -> 4 blocks/CU at (256,4).
// ---------------------------------------------------------------------------
__global__ __launch_bounds__(256, 4)
void ffn1_kernel(const ushort_t* __restrict__ A, const ushort_t* __restrict__ W1t,
                 const float* __restrict__ bias1, ushort_t* __restrict__ hid,
                 int M)
{
    __shared__ short As[2][64 * 32];
    __shared__ short Bs[2][256 * 32];
    const int K = 256;
    int t    = threadIdx.x;
    int nc   = blockIdx.x;            // hidden chunk 0..3
    int row0 = blockIdx.y * 64;
    int lane = t & 63;
    int w    = t >> 6;
    int wn   = w * 64;
    const int quad = lane >> 4, lrow = lane & 15;

    f32x4 acc[4][4];
    #pragma unroll
    for (int i = 0; i < 4; ++i)
        #pragma unroll
        for (int j = 0; j < 4; ++j)
            acc[i][j] = (f32x4){0.f, 0.f, 0.f, 0.f};

    int srow = lane >> 2;
    const int sw = (((lane & 3) ^ ((lane >> 3) & 3)) * 8);
    const int rs = ((quad ^ ((lrow >> 1) & 3)) * 8);
    const ushort_t* Ag = A + (size_t)(row0 + w * 16 + srow) * K + sw;
    const ushort_t* Bg = W1t + (size_t)(nc * 256 + w * 64 + srow) * K + sw;

    gload16(Ag, (ushort_t*)&As[0][(w * 16) * 32]);
    #pragma unroll
    for (int q = 0; q < 4; ++q)
        gload16(Bg + (size_t)(q * 16) * K,
                (ushort_t*)&Bs[0][(w * 64 + q * 16) * 32]);

    #pragma unroll
    for (int k0 = 0; k0 < K; k0 += 32) {
        const int cur = (k0 >> 5) & 1;
        __syncthreads();
        if (k0 + 32 < K) {
            const int nxt = cur ^ 1;
            gload16(Ag + k0 + 32, (ushort_t*)&As[nxt][(w * 16) * 32]);
            #pragma unroll
            for (int q = 0; q < 4; ++q)
                gload16(Bg + (size_t)(q * 16) * K + k0 + 32,
                        (ushort_t*)&Bs[nxt][(w * 64 + q * 16) * 32]);
        }
        bf16x8 af[4], bfr[4];
        #pragma unroll
        for (int i = 0; i < 4; ++i)
            af[i] = *(const bf16x8*)&As[cur][(i * 16 + lrow) * 32 + rs];
        #pragma unroll
        for (int j = 0; j < 4; ++j)
            bfr[j] = *(const bf16x8*)&Bs[cur][(wn + j * 16 + lrow) * 32 + rs];
        #pragma unroll
        for (int i = 0; i < 4; ++i)
            #pragma unroll
            for (int j = 0; j < 4; ++j)
                acc[i][j] = __builtin_amdgcn_mfma_f32_16x16x32_bf16(af[i], bfr[j], acc[i][j], 0, 0, 0);
    }

    #pragma unroll
    for (int j = 0; j < 4; ++j) {
        int col  = wn + j * 16 + lrow;
        int gcol = nc * 256 + col;
        float b1v = bias1[gcol];
        #pragma unroll
        for (int i = 0; i < 4; ++i)
            #pragma unroll
            for (int rg = 0; rg < 4; ++rg) {
                int row = row0 + i * 16 + quad * 4 + rg;
                if (row < M)
                    hid[(size_t)row * 1024 + gcol] =
                        f2bf(fmaxf(acc[i][j][rg] + b1v, 0.f));
            }
    }
}

// ---------------------------------------------------------------------------
// FFN part 2: x = LN2(x + hid@W2 + b2); writes x, xb, qb.
// 64x256 tile, K=1024 (32 steps). Epilogue = gemm_ln LN extended to 64 rows.
// LDS 40KB -> 4 blocks/CU at (256,4). red aliased onto As[0] (2560B<=4096B;
// As[0] last read at k0=960, drained by the k0=992 barrier).
// ---------------------------------------------------------------------------
__global__ __launch_bounds__(256, 4)
void ffn2_kernel(const ushort_t* __restrict__ hid, const ushort_t* __restrict__ W2t,
                 const float* __restrict__ bias2,
                 float* __restrict__ x, ushort_t* __restrict__ xb,
                 ushort_t* __restrict__ qb, const ushort_t* __restrict__ posb,
                 const float* __restrict__ lng, const float* __restrict__ lnb,
                 int M)
{
    __shared__ short As[2][64 * 32];
    __shared__ short Bs[2][256 * 32];
    float* red1 = (float*)&As[0][0];          // 320 floats
    float* red2 = red1 + 64 * 5;              // 2560B <= 4096B of As[0]
    const int K = 1024;
    int t    = threadIdx.x;
    int row0 = blockIdx.x * 64;
    int lane = t & 63;
    int w    = t >> 6;
    int wn   = w * 64;
    const int quad = lane >> 4, lrow = lane & 15;

    f32x4 acc[4][4];
    #pragma unroll
    for (int i = 0; i < 4; ++i)
        #pragma unroll
        for (int j = 0; j < 4; ++j)
            acc[i][j] = (f32x4){0.f, 0.f, 0.f, 0.f};

    int srow = lane >> 2;
    const int sw = (((lane & 3) ^ ((lane >> 3) & 3)) * 8);
    const int rs = ((quad ^ ((lrow >> 1) & 3)) * 8);
    const ushort_t* Ag = hid + (size_t)(row0 + w * 16 + srow) * K + sw;
    const ushort_t* Bg = W2t + (size_t)(w * 64 + srow) * K + sw;

    gload16(Ag, (ushort_t*)&As[0][(w * 16) * 32]);
    #pragma unroll
    for (int q = 0; q < 4; ++q)
        gload16(Bg + (size_t)(q * 16) * K,
                (ushort_t*)&Bs[0][(w * 64 + q * 16) * 32]);

    #pragma unroll 4
    for (int k0 = 0; k0 < K; k0 += 32) {
        const int cur = (k0 >> 5) & 1;
        __syncthreads();
        if (k0 + 32 < K) {
            const int nxt = cur ^ 1;
            gload16(Ag + k0 + 32, (ushort_t*)&As[nxt][(w * 16) * 32]);
            #pragma unroll
            for (int q = 0; q < 4; ++q)
                gload16(Bg + (size_t)(q * 16) * K + k0 + 32,
                        (ushort_t*)&Bs[nxt][(w * 64 + q * 16) * 32]);
        }
        bf16x8 af[4], bfr[4];
        #pragma unroll
        for (int i = 0; i < 4; ++i)
            af[i] = *(const bf16x8*)&As[cur][(i * 16 + lrow) * 32 + rs];
        #pragma unroll
        for (int j = 0; j < 4; ++j)
            bfr[j] = *(const bf16x8*)&Bs[cur][(wn + j * 16 + lrow) * 32 + rs];
        #pragma unroll
        for (int i = 0; i < 4; ++i)
            #pragma unroll
            for (int j = 0; j < 4; ++j)
                acc[i][j] = __builtin_amdgcn_mfma_f32_16x16x32_bf16(af[i], bfr[j], acc[i][j], 0, 0, 0);
    }

    // ---- fused epilogue: v = x + (y + bias2); LN2; write x, xb, qb ----
    float gj[4], bj[4], bi[4];
    #pragma unroll
    for (int j = 0; j < 4; ++j) {
        int col = wn + j * 16 + lrow;
        gj[j] = lng[col];
        bj[j] = lnb[col];
        bi[j] = bias2[col];
    }

    #pragma unroll
    for (int i = 0; i < 4; ++i)
        #pragma unroll
        for (int rg = 0; rg < 4; ++rg) {
            int row = row0 + i * 16 + quad * 4 + rg;
            #pragma unroll
            for (int j = 0; j < 4; ++j) {
                int col = wn + j * 16 + lrow;
                float xres = (row < M) ? x[(size_t)row * 256 + col] : 0.f;
                acc[i][j][rg] += bi[j] + xres;
            }
            float p1 = acc[i][0][rg] + acc[i][1][rg] + acc[i][2][rg] + acc[i][3][rg];
            float p2 = acc[i][0][rg] * acc[i][0][rg] + acc[i][1][rg] * acc[i][1][rg]
                     + acc[i][2][rg] * acc[i][2][rg] + acc[i][3][rg] * acc[i][3][rg];
            p1 += __shfl_xor(p1, 1); p2 += __shfl_xor(p2, 1);
            p1 += __shfl_xor(p1, 2); p2 += __shfl_xor(p2, 2);
            p1 += __shfl_xor(p1, 4); p2 += __shfl_xor(p2, 4);
            p1 += __shfl_xor(p1, 8); p2 += __shfl_xor(p2, 8);
            if (lrow == 0) {
                int rl = i * 16 + quad * 4 + rg;
                red1[rl * 5 + w] = p1;
                red2[rl * 5 + w] = p2;
            }
        }
    __syncthreads();

    #pragma unroll
    for (int i = 0; i < 4; ++i)
        #pragma unroll
        for (int rg = 0; rg < 4; ++rg) {
            int rl = i * 16 + quad * 4 + rg;
            float S1 = red1[rl * 5 + 0] + red1[rl * 5 + 1] + red1[rl * 5 + 2] + red1[rl * 5 + 3];
            float S2 = red2[rl * 5 + 0] + red2[rl * 5 + 1] + red2[rl * 5 + 2] + red2[rl * 5 + 3];
            float mean = S1 * (1.f / 256);
            float rstd = rsqrtf(S2 * (1.f / 256) - mean * mean + 1e-5f);
            int row = row0 + rl;
            if (row < M) {
                #pragma unroll
                for (int j = 0; j < 4; ++j) {
                    int col = wn + j * 16 + lrow;
                    float out = (acc[i][j][rg] - mean) * rstd * gj[j] + bj[j];
                    size_t o = (size_t)row * 256 + col;
                    x[o]  = out;
                    xb[o] = f2bf(out);
                    qb[o] = f2bf(out + bf2f(posb[o]));
                }
            }
        }
}

// ---------------------------------------------------------------------------
// Fused deformable sampling, v7: XCD-pinned heads + 16B-lane gathers +
// relaxed VGPR cap for deep load pipelining.
// ---------------------------------------------------------------------------
__global__ __launch_bounds__(256, 4)
void sample_kernel(const ushort_t* __restrict__ valueb,
                   const ushort_t* __restrict__ offh,   // [NH][M][48]
                   const ushort_t* __restrict__ attnh,  // [NH][M][16]
                   ushort_t* __restrict__ sampb)
{
    __shared__ float wrec[16 * 168];
    __shared__ int   idxA[16 * 40];

    const int LD_[4]  = {4, 2, 1, 1};
    const int LH_[4]  = {48, 24, 12, 6};
    const int LW_[4]  = {48, 24, 12, 6};
    const int LS0_[4] = {0, 9216, 10368, 10512};

    int t   = threadIdx.x;
    int gl  = t >> 4;                   // local group 0..15
    int sub = t & 15;
    int h   = blockIdx.x;
    int r   = blockIdx.y * 16 + gl;
    bool valid = (r < M_ROWS);
    if (!valid) r = M_ROWS - 1;
    int b   = (r >= S_TOT) ? 1 : 0;
    int s   = r - b * S_TOT;

    float rx, ry, rz;
    {
        int j;
        if (s < 9216)       { j = s;         int qx = j % 48; int q2 = j / 48; int qy = q2 % 48; int qz = q2 / 48;
                              rx = (qx + 0.5f) * (1.f/48); ry = (qy + 0.5f) * (1.f/48); rz = (qz + 0.5f) * (1.f/4); }
        else if (s < 10368) { j = s - 9216;  int qx = j % 24; int q2 = j / 24; int qy = q2 % 24; int qz = q2 / 24;
                              rx = (qx + 0.5f) * (1.f/24); ry = (qy + 0.5f) * (1.f/24); rz = (qz + 0.5f) * (1.f/2); }
        else if (s < 10512) { j = s - 10368; int qx = j % 12; int qy = j / 12;
                              rx = (qx + 0.5f) * (1.f/12); ry = (qy + 0.5f) * (1.f/12); rz = 0.5f; }
        else                { j = s - 10512; int qx = j % 6;  int qy = j / 6;
                              rx = (qx + 0.5f) * (1.f/6);  ry = (qy + 0.5f) * (1.f/6);  rz = 0.5f; }
    }

    // ---- phase 1: one point per lane ----
    {
        int p = sub;
        float lg = bf2f(attnh[((size_t)h * M_ROWS + r) * 16 + p]);
        float mx = lg;
        mx = fmaxf(mx, __shfl_xor(mx, 1));
        mx = fmaxf(mx, __shfl_xor(mx, 2));
        mx = fmaxf(mx, __shfl_xor(mx, 4));
        mx = fmaxf(mx, __shfl_xor(mx, 8));
        float e = __expf(lg - mx);
        float sm = e;
        sm += __shfl_xor(sm, 1);
        sm += __shfl_xor(sm, 2);
        sm += __shfl_xor(sm, 4);
        sm += __shfl_xor(sm, 8);
        float aw = e / sm;

        int lvl = p >> 2;
        const int Dl = LD_[lvl], Hl = LH_[lvl], Wl = LW_[lvl];
        size_t base3 = ((size_t)h * M_ROWS + r) * 48 + p * 3;
        float cx = rx * Wl + bf2f(offh[base3 + 0]) - 0.5f;
        float cy = ry * Hl + bf2f(offh[base3 + 1]) - 0.5f;
        float cz = rz * Dl + bf2f(offh[base3 + 2]) - 0.5f;
        float xf = floorf(cx), yf = floorf(cy), zf = floorf(cz);
        float fx = cx - xf, fy = cy - yf, fz = cz - zf;
        int x0 = (int)xf, y0 = (int)yf, z0 = (int)zf;
        float wx0 = ((unsigned)x0       < (unsigned)Wl) ? 1.f - fx : 0.f;
        float wx1 = ((unsigned)(x0 + 1) < (unsigned)Wl) ? fx       : 0.f;
        float wy0 = ((unsigned)y0       < (unsigned)Hl) ? 1.f - fy : 0.f;
        float wy1 = ((unsigned)(y0 + 1) < (unsigned)Hl) ? fy       : 0.f;
        float wz0 = ((unsigned)z0       < (unsigned)Dl) ? (1.f - fz) * aw : 0.f;
        float wz1 = ((unsigned)(z0 + 1) < (unsigned)Dl) ? fz * aw       : 0.f;
        int xc = min(max(x0, -1), Wl - 1);
        int yc = min(max(y0, -1), Hl - 1);
        int zc = min(max(z0, -1), Dl - 1);
        int idx = LS0_[lvl] + (zc * Hl + yc) * Wl + xc;

        float* wp = &wrec[gl * 168 + p * 8];
        *(f32x4*)wp       = (f32x4){wz0 * wy0 * wx0, wz0 * wy0 * wx1,
                                    wz0 * wy1 * wx0, wz0 * wy1 * wx1};
        *(f32x4*)(wp + 4) = (f32x4){wz1 * wy0 * wx0, wz1 * wy0 * wx1,
                                    wz1 * wy1 * wx0, wz1 * wy1 * wx1};
        idxA[gl * 40 + p] = idx;
    }
    __syncthreads();

    // ---- phase 2: corner cr = (dy,dx), channel octet q ----
    int q  = sub & 3;
    int cr = sub >> 2;
    int dy = cr >> 1, dx = cr & 1;
    const ushort_t* vb = valueb + ((size_t)(b * NH_DIM + h) * S_TOT) * HD_DIM + q * 8;
    f32x4 accA = (f32x4){0.f, 0.f, 0.f, 0.f};
    f32x4 accB = (f32x4){0.f, 0.f, 0.f, 0.f};

    #pragma unroll
    for (int p = 0; p < 16; ++p) {
        const int lvl = p >> 2;
        const int Wl = LW_[lvl];
        const int HW = LH_[lvl] * LW_[lvl];
        float w0 = wrec[gl * 168 + p * 8 + cr];
        float w1 = wrec[gl * 168 + p * 8 + 4 + cr];
        int idx = idxA[gl * 40 + p] + dy * Wl + dx;
        const ushort_t* cb = vb + (long long)idx * HD_DIM;
        uint4 u0 = *(const uint4*)cb;
        uint4 u1 = *(const uint4*)(cb + HW * HD_DIM);
        accA += w0 * up2(u0.x, u0.y);
        accB += w0 * up2(u0.z, u0.w);
        accA += w1 * up2(u1.x, u1.y);
        accB += w1 * up2(u1.z, u1.w);
    }

    accA.x += __shfl_xor(accA.x, 4); accA.y += __shfl_xor(accA.y, 4);
    accA.z += __shfl_xor(accA.z, 4); accA.w += __shfl_xor(accA.w, 4);
    accB.x += __shfl_xor(accB.x, 4); accB.y += __shfl_xor(accB.y, 4);
    accB.z += __shfl_xor(accB.z, 4); accB.w += __shfl_xor(accB.w, 4);
    accA.x += __shfl_xor(accA.x, 8); accA.y += __shfl_xor(accA.y, 8);
    accA.z += __shfl_xor(accA.z, 8); accA.w += __shfl_xor(accA.w, 8);
    accB.x += __shfl_xor(accB.x, 8); accB.y += __shfl_xor(accB.y, 8);
    accB.z += __shfl_xor(accB.z, 8); accB.w += __shfl_xor(accB.w, 8);

    if (cr == 0 && valid) {
        ushort4 o1, o2;
        o1.x = f2bf(accA.x); o1.y = f2bf(accA.y); o1.z = f2bf(accA.z); o1.w = f2bf(accA.w);
        o2.x = f2bf(accB.x); o2.y = f2bf(accB.y); o2.z = f2bf(accB.z); o2.w = f2bf(accB.w);
        ushort_t* op = sampb + (size_t)r * E_DIM + h * HD_DIM + q * 8;
        *(ushort4*)op       = o1;
        *(ushort4*)(op + 4) = o2;
    }
}

// ---------------------------------------------------------------------------
extern "C" void kernel_launch(void* const* d_in, const int* in_sizes, int n_in,
                              void* d_out, int out_size, void* d_ws, size_t ws_size,
                              hipStream_t stream)
{
    const float* f0     = (const float*)d_in[0];
    const float* p0     = (const float*)d_in[1];
    const float* f1     = (const float*)d_in[2];
    const float* p1     = (const float*)d_in[3];
    const float* f2     = (const float*)d_in[4];
    const float* p2     = (const float*)d_in[5];
    const float* f3     = (const float*)d_in[6];
    const float* p3     = (const float*)d_in[7];
    const float* lemb   = (const float*)d_in[8];
    const float* W_off  = (const float*)d_in[9];
    const float* b_off  = (const float*)d_in[10];
    const float* W_attn = (const float*)d_in[11];
    const float* b_attn = (const float*)d_in[12];
    const float* W_val  = (const float*)d_in[13];
    const float* b_val  = (const float*)d_in[14];
    const float* W_out  = (const float*)d_in[15];
    const float* b_out  = (const float*)d_in[16];
    const float* ln1_g  = (const float*)d_in[17];
    const float* ln1_b  = (const float*)d_in[18];
    const float* W_ff1  = (const float*)d_in[19];
    const float* b_ff1  = (const float*)d_in[20];
    const float* W_ff2  = (const float*)d_in[21];
    const float* b_ff2  = (const float*)d_in[22];
    const float* ln2_g  = (const float*)d_in[23];
    const float* ln2_b  = (const float*)d_in[24];

    float* x = (float*)d_out;
    char*  w = (char*)d_ws;

    // ws layout (bytes)
    ushort_t* posb   = (ushort_t*)(w + 0);                   // 10,813,440
    // value region: 256KB front guard | (B,NH,S,HD) bf16 | 128KB back guard
    ushort_t* valueb = (ushort_t*)(w + 21626880 + 262144);
    char*     region =            (w + 34525184);            // 43,253,760
    ushort_t* offh   = (ushort_t*)(region);                  // [NH][M][48] 16,220,160
    ushort_t* attnh  = (ushort_t*)(region + 16220160);       // [NH][M][16]  5,406,720
    ushort_t* sampb  = (ushort_t*)(region + 21626880);       // 10,813,440
    // hidden[M_PAD][1024] bf16 = 43,253,760 B aliases the ENTIRE region:
    // offh/attnh dead after sample_kernel, sampb dead after gemm_ln; next
    // layer's gemm_part1/sample rewrite them fresh.
    ushort_t* hidden = (ushort_t*)(region);
    ushort_t* xb     = (ushort_t*)(w + 77778944);            // 10,813,440
    ushort_t* qb     = (ushort_t*)(w + 88592384);            // 10,813,440
    ushort_t* wb     = (ushort_t*)(w + 99405824);            //  9,437,184

    // Combined attention weight: per layer 768 rows x 256 K
    ushort_t* Wc_t = wb;              // [6][768][256]
    ushort_t* Wp_t = wb + 1179648;    // [6][256][256]
    ushort_t* W1_t = wb + 1572864;    // [6][1024][256]
    ushort_t* W2_t = wb + 3145728;    // [6][256][1024]

    dim3 blk(256);

    transpose_cvt_kernel<<<dim3(8, 8, 6),  blk, 0, stream>>>(W_val,  Wc_t, 256, 256,  196608, 0);
    transpose_cvt_kernel<<<dim3(12, 8, 6), blk, 0, stream>>>(W_off,  Wc_t, 256, 384,  196608, 256);
    transpose_cvt_kernel<<<dim3(4, 8, 6),  blk, 0, stream>>>(W_attn, Wc_t, 256, 128,  196608, 640);
    transpose_cvt_kernel<<<dim3(8, 8, 6),  blk, 0, stream>>>(W_out,  Wp_t, 256, 256,   65536, 0);
    transpose_cvt_kernel<<<dim3(32, 8, 6), blk, 0, stream>>>(W_ff1,  W1_t, 256, 1024, 262144, 0);
    transpose_cvt_kernel<<<dim3(8, 32, 6), blk, 0, stream>>>(W_ff2,  W2_t, 1024, 256, 262144, 0);

    // 331 j-tiles (288+36+5+2), 8 e-tiles, 2 batches
    assemble_kernel<<<dim3(331, 8, 2), blk, 0, stream>>>(
        f0, p0, f1, p1, f2, p2, f3, p3, lemb, x, posb, xb, qb);

    const int MT = M_PAD / 64;               // 330
    const int LT = M_PAD / 32;               // 660 (gemm_ln grid)
    const int SB = (M_ROWS + 15) / 16;       // 1319
    for (int l = 0; l < NLAYERS; ++l) {
        gemm_part1<<<dim3(3, MT), blk, 0, stream>>>(
            xb, qb, Wc_t + l * 196608,
            b_val + l * 256, b_off + l * 384, b_attn + l * 128,
            valueb, offh, attnh, M_ROWS);
        sample_kernel<<<dim3(NH_DIM, SB), blk, 0, stream>>>(valueb, offh, attnh, sampb);
        gemm_ln<<<LT, blk, 0, stream>>>(
            sampb, Wp_t + l * 65536, b_out + l * 256,
            x, xb, ln1_g + l * 256, ln1_b + l * 256, M_ROWS);
        ffn1_kernel<<<dim3(4, MT), blk, 0, stream>>>(
            xb, W1_t + l * 262144, b_ff1 + l * 1024, hidden, M_ROWS);
        ffn2_kernel<<<MT, blk, 0, stream>>>(
            hidden, W2_t + l * 262144, b_ff2 + l * 256,
            x, xb, qb, posb,
            ln2_g + l * 256, ln2_b + l * 256, M_ROWS);
    }
}

// Round 11
// 1260.721 us; speedup vs baseline: 1.0284x; 1.0284x over previous
//
#include <hip/hip_runtime.h>

#define S_TOT   10548
#define M_ROWS  21096
#define M_PAD   21120          // 330*64 = 660*32
#define E_DIM   256
#define NH_DIM  8
#define HD_DIM  32
#define DF_DIM  1024
#define NLAYERS 6

typedef unsigned short ushort_t;
typedef __attribute__((ext_vector_type(8))) short bf16x8;
typedef __attribute__((ext_vector_type(4))) float f32x4;

__device__ inline ushort_t f2bf(float f) {
    unsigned u = __float_as_uint(f);
    u += 0x7FFF + ((u >> 16) & 1);          // RNE
    return (ushort_t)(u >> 16);
}
__device__ inline float bf2f(ushort_t h) {
    return __uint_as_float(((unsigned)h) << 16);
}
__device__ inline f32x4 up2(unsigned a, unsigned b) {
    f32x4 v;
    v.x = __uint_as_float(a << 16);
    v.y = __uint_as_float(a & 0xffff0000u);
    v.z = __uint_as_float(b << 16);
    v.w = __uint_as_float(b & 0xffff0000u);
    return v;
}
// async global->LDS, 16B per lane; LDS dest wave-uniform, lane scatters at
// dest + lane*16.
__device__ inline void gload16(const ushort_t* g, ushort_t* l) {
    __builtin_amdgcn_global_load_lds(
        (const __attribute__((address_space(1))) void*)g,
        (__attribute__((address_space(3))) void*)l, 16, 0, 0);
}
// counted-vmcnt waits (T4): stage(k) complete, younger stages stay in flight.
#define VMCNT4 asm volatile("s_waitcnt vmcnt(4)" ::: "memory")
#define VMCNT0 asm volatile("s_waitcnt vmcnt(0)" ::: "memory")
// raw workgroup barrier WITHOUT the __syncthreads vmcnt(0) drain.
__device__ inline void rawbar() {
    asm volatile("" ::: "memory");
    __builtin_amdgcn_s_barrier();
    asm volatile("" ::: "memory");
}

// ---------------------------------------------------------------------------
// Input assembly v2: LDS-transpose tiles, both sides coalesced.
// grid = (331 j-tiles, 8 e-tiles, 2 batches).
// ---------------------------------------------------------------------------
__global__ __launch_bounds__(256)
void assemble_kernel(const float* __restrict__ f0, const float* __restrict__ p0,
                     const float* __restrict__ f1, const float* __restrict__ p1,
                     const float* __restrict__ f2, const float* __restrict__ p2,
                     const float* __restrict__ f3, const float* __restrict__ p3,
                     const float* __restrict__ lemb,
                     float* __restrict__ x, ushort_t* __restrict__ posb,
                     ushort_t* __restrict__ xb, ushort_t* __restrict__ qb)
{
    __shared__ float tf[32][33];
    __shared__ float tp[32][33];

    int tb = blockIdx.x;
    int e0 = blockIdx.y * 32;
    int b  = blockIdx.z;
    int lvl, j0, n, s0; const float* f; const float* p;
    if (tb < 288)      { lvl = 0; j0 = tb * 32;         n = 9216; s0 = 0;     f = f0; p = p0; }
    else if (tb < 324) { lvl = 1; j0 = (tb - 288) * 32; n = 1152; s0 = 9216;  f = f1; p = p1; }
    else if (tb < 329) { lvl = 2; j0 = (tb - 324) * 32; n = 144;  s0 = 10368; f = f2; p = p2; }
    else               { lvl = 3; j0 = (tb - 329) * 32; n = 36;   s0 = 10512; f = f3; p = p3; }

    int tx = threadIdx.x & 31, ty = threadIdx.x >> 5;
    bool jv = (j0 + tx) < n;
    size_t base = (size_t)(b * E_DIM + e0) * n + j0 + tx;
    #pragma unroll
    for (int i = 0; i < 4; ++i) {
        int e = ty + i * 8;
        float fv = 0.f, pv = 0.f;
        if (jv) {
            fv = f[base + (size_t)e * n];
            pv = p[base + (size_t)e * n];
        }
        tf[e][tx] = fv;
        tp[e][tx] = pv;
    }
    __syncthreads();

    float lv = lemb[lvl * E_DIM + e0 + tx];
    #pragma unroll
    for (int i = 0; i < 4; ++i) {
        int jl = ty + i * 8;
        if (j0 + jl < n) {
            int r = b * S_TOT + s0 + j0 + jl;
            float xv = tf[tx][jl];
            float pv = tp[tx][jl] + lv;
            size_t o = (size_t)r * E_DIM + e0 + tx;
            x[o]    = xv;
            posb[o] = f2bf(pv);
            xb[o]   = f2bf(xv);
            qb[o]   = f2bf(xv + pv);
        }
    }
}

// ---------------------------------------------------------------------------
// Weight convert+transpose: src f32 [L,K,N] -> dst bf16 [L(stride), rowOff+N, K]
// ---------------------------------------------------------------------------
__global__ __launch_bounds__(256)
void transpose_cvt_kernel(const float* __restrict__ src, ushort_t* __restrict__ dst,
                          int K, int N, int dstLayerStride, int dstRowOff)
{
    __shared__ float tile[32][33];
    int l  = blockIdx.z;
    int n0 = blockIdx.x * 32, k0 = blockIdx.y * 32;
    int tx = threadIdx.x & 31, ty = threadIdx.x >> 5;
    const float* s = src + (size_t)l * K * N;
    ushort_t* d    = dst + (size_t)l * dstLayerStride + (size_t)dstRowOff * K;
    #pragma unroll
    for (int i = 0; i < 32; i += 8)
        tile[ty + i][tx] = s[(size_t)(k0 + ty + i) * N + n0 + tx];
    __syncthreads();
    #pragma unroll
    for (int i = 0; i < 32; i += 8)
        d[(size_t)(n0 + ty + i) * K + k0 + tx] = f2bf(tile[tx][ty + i]);
}

// ---------------------------------------------------------------------------
// 64x256-tile bf16 MFMA GEMM (part1), double-buffered single-sync K-loop.
// grid.x=sup: 0=value (A=xb, permute store), 1=off[0:256),
// 2=off[256:384)+attn (A=qb); off/attn stored HEAD-MAJOR.
// ---------------------------------------------------------------------------
__global__ __launch_bounds__(256, 2)
void gemm_part1(const ushort_t* __restrict__ A0, const ushort_t* __restrict__ A1,
                const ushort_t* __restrict__ BtBase,
                const float* __restrict__ b1, const float* __restrict__ b2,
                const float* __restrict__ b3,
                ushort_t* __restrict__ O1, ushort_t* __restrict__ O2,
                ushort_t* __restrict__ O3, int M)
{
    __shared__ short As[2][64 * 32];
    __shared__ short Bs[2][256 * 32];
    const int K = 256;
    int t    = threadIdx.x;
    int sup  = blockIdx.x;
    int row0 = blockIdx.y * 64;
    int lane = t & 63;
    int w    = t >> 6;
    int wn   = w * 64;
    const int quad = lane >> 4, lrow = lane & 15;

    const ushort_t* A  = (sup != 0) ? A1 : A0;
    const ushort_t* Bt = BtBase + (size_t)sup * 256 * K;

    f32x4 acc[4][4];
    #pragma unroll
    for (int i = 0; i < 4; ++i)
        #pragma unroll
        for (int j = 0; j < 4; ++j)
            acc[i][j] = (f32x4){0.f, 0.f, 0.f, 0.f};

    int srow = lane >> 2;
    const int sw = (((lane & 3) ^ ((lane >> 3) & 3)) * 8);     // swizzled k-seg
    const int rs = ((quad ^ ((lrow >> 1) & 3)) * 8);           // fragment slot
    const ushort_t* Ag = A + (size_t)(row0 + w * 16 + srow) * K + sw;
    const ushort_t* Bg = Bt + (size_t)(w * 64 + srow) * K + sw;

    // prologue: stage k0=0 into buffer 0
    gload16(Ag, (ushort_t*)&As[0][(w * 16) * 32]);
    #pragma unroll
    for (int q = 0; q < 4; ++q)
        gload16(Bg + (size_t)(q * 16) * K,
                (ushort_t*)&Bs[0][(w * 64 + q * 16) * 32]);

    #pragma unroll
    for (int k0 = 0; k0 < K; k0 += 32) {
        const int cur = (k0 >> 5) & 1;
        __syncthreads();                      // stage(k) landed; buf cur^1 free
        if (k0 + 32 < K) {
            const int nxt = cur ^ 1;
            gload16(Ag + k0 + 32, (ushort_t*)&As[nxt][(w * 16) * 32]);
            #pragma unroll
            for (int q = 0; q < 4; ++q)
                gload16(Bg + (size_t)(q * 16) * K + k0 + 32,
                        (ushort_t*)&Bs[nxt][(w * 64 + q * 16) * 32]);
        }
        bf16x8 af[4], bfr[4];
        #pragma unroll
        for (int i = 0; i < 4; ++i)
            af[i] = *(const bf16x8*)&As[cur][(i * 16 + lrow) * 32 + rs];
        #pragma unroll
        for (int j = 0; j < 4; ++j)
            bfr[j] = *(const bf16x8*)&Bs[cur][(wn + j * 16 + lrow) * 32 + rs];
        #pragma unroll
        for (int i = 0; i < 4; ++i)
            #pragma unroll
            for (int j = 0; j < 4; ++j)
                acc[i][j] = __builtin_amdgcn_mfma_f32_16x16x32_bf16(af[i], bfr[j], acc[i][j], 0, 0, 0);
    }

    #pragma unroll
    for (int j = 0; j < 4; ++j) {
        int col = wn + j * 16 + lrow;     // 0..255 local
        float bia = (sup == 0) ? b1[col]
                  : (sup == 1) ? b2[col]
                  : (col < 128) ? b2[256 + col] : b3[col - 128];
        #pragma unroll
        for (int i = 0; i < 4; ++i)
            #pragma unroll
            for (int rg = 0; rg < 4; ++rg) {
                int row = row0 + i * 16 + quad * 4 + rg;
                if (row < M) {
                    float v = acc[i][j][rg] + bia;
                    if (sup == 0) {
                        int b = (row >= S_TOT) ? 1 : 0;
                        int s = row - b * S_TOT;
                        O1[(((size_t)(b * NH_DIM + (col >> 5))) * S_TOT + s) * HD_DIM + (col & 31)] = f2bf(v);
                    } else if (sup == 2 && col >= 128) {
                        int acol = col - 128;
                        O3[((size_t)(acol >> 4) * M_ROWS + row) * 16 + (acol & 15)] = f2bf(v);
                    } else {
                        int ocol = (sup == 1) ? col : 256 + col;
                        int hh = (ocol * 1366) >> 16;            // /48
                        O2[((size_t)hh * M_ROWS + row) * 48 + (ocol - hh * 48)] = f2bf(v);
                    }
                }
            }
    }
}

// ---------------------------------------------------------------------------
// 32x256-tile bf16 MFMA GEMM + FUSED residual + LayerNorm epilogue (out-proj).
// Double-buffered single-sync K-loop; red scratch aliased onto As[0].
// LDS 36KB -> 4 blocks/CU.
// ---------------------------------------------------------------------------
__global__ __launch_bounds__(256, 4)
void gemm_ln(const ushort_t* __restrict__ A, const ushort_t* __restrict__ Bt,
             const float* __restrict__ bias,
             float* __restrict__ x, ushort_t* __restrict__ xb,
             const float* __restrict__ lng, const float* __restrict__ lnb,
             int M)
{
    __shared__ short As[2][32 * 32];
    __shared__ short Bs[2][256 * 32];
    float* red1 = (float*)&As[0][0];          // 160 floats
    float* red2 = red1 + 32 * 5;              // 160 floats (1280B <= 2048B)
    const int K = 256;
    int t    = threadIdx.x;
    int row0 = blockIdx.x * 32;
    int lane = t & 63;
    int w    = t >> 6;
    int wn   = w * 64;
    const int quad = lane >> 4, lrow = lane & 15;

    f32x4 acc[2][4];
    #pragma unroll
    for (int i = 0; i < 2; ++i)
        #pragma unroll
        for (int j = 0; j < 4; ++j)
            acc[i][j] = (f32x4){0.f, 0.f, 0.f, 0.f};

    int srow = lane >> 2;
    const int sw = (((lane & 3) ^ ((lane >> 3) & 3)) * 8);
    const int rs = ((quad ^ ((lrow >> 1) & 3)) * 8);
    const ushort_t* Ag = A + (size_t)(row0 + w * 16 + srow) * K + sw;   // w<2
    const ushort_t* Bg = Bt + (size_t)(w * 64 + srow) * K + sw;

    if (w < 2) gload16(Ag, (ushort_t*)&As[0][(w * 16) * 32]);
    #pragma unroll
    for (int q = 0; q < 4; ++q)
        gload16(Bg + (size_t)(q * 16) * K,
                (ushort_t*)&Bs[0][(w * 64 + q * 16) * 32]);

    #pragma unroll
    for (int k0 = 0; k0 < K; k0 += 32) {
        const int cur = (k0 >> 5) & 1;
        __syncthreads();
        if (k0 + 32 < K) {
            const int nxt = cur ^ 1;
            if (w < 2) gload16(Ag + k0 + 32, (ushort_t*)&As[nxt][(w * 16) * 32]);
            #pragma unroll
            for (int q = 0; q < 4; ++q)
                gload16(Bg + (size_t)(q * 16) * K + k0 + 32,
                        (ushort_t*)&Bs[nxt][(w * 64 + q * 16) * 32]);
        }
        bf16x8 af[2], bfr[4];
        #pragma unroll
        for (int i = 0; i < 2; ++i)
            af[i] = *(const bf16x8*)&As[cur][(i * 16 + lrow) * 32 + rs];
        #pragma unroll
        for (int j = 0; j < 4; ++j)
            bfr[j] = *(const bf16x8*)&Bs[cur][(wn + j * 16 + lrow) * 32 + rs];
        #pragma unroll
        for (int i = 0; i < 2; ++i)
            #pragma unroll
            for (int j = 0; j < 4; ++j)
                acc[i][j] = __builtin_amdgcn_mfma_f32_16x16x32_bf16(af[i], bfr[j], acc[i][j], 0, 0, 0);
    }

    // ---- fused epilogue: v = x + (y + bias); LayerNorm per row ----
    float gj[4], bj[4], bi[4];
    #pragma unroll
    for (int j = 0; j < 4; ++j) {
        int col = wn + j * 16 + lrow;
        gj[j] = lng[col];
        bj[j] = lnb[col];
        bi[j] = bias[col];
    }

    #pragma unroll
    for (int i = 0; i < 2; ++i)
        #pragma unroll
        for (int rg = 0; rg < 4; ++rg) {
            int row = row0 + i * 16 + quad * 4 + rg;
            #pragma unroll
            for (int j = 0; j < 4; ++j) {
                int col = wn + j * 16 + lrow;
                float xres = (row < M) ? x[(size_t)row * 256 + col] : 0.f;
                acc[i][j][rg] += bi[j] + xres;
            }
            float p1 = acc[i][0][rg] + acc[i][1][rg] + acc[i][2][rg] + acc[i][3][rg];
            float p2 = acc[i][0][rg] * acc[i][0][rg] + acc[i][1][rg] * acc[i][1][rg]
                     + acc[i][2][rg] * acc[i][2][rg] + acc[i][3][rg] * acc[i][3][rg];
            p1 += __shfl_xor(p1, 1); p2 += __shfl_xor(p2, 1);
            p1 += __shfl_xor(p1, 2); p2 += __shfl_xor(p2, 2);
            p1 += __shfl_xor(p1, 4); p2 += __shfl_xor(p2, 4);
            p1 += __shfl_xor(p1, 8); p2 += __shfl_xor(p2, 8);
            if (lrow == 0) {
                int rl = i * 16 + quad * 4 + rg;
                red1[rl * 5 + w] = p1;
                red2[rl * 5 + w] = p2;
            }
        }
    __syncthreads();

    #pragma unroll
    for (int i = 0; i < 2; ++i)
        #pragma unroll
        for (int rg = 0; rg < 4; ++rg) {
            int rl = i * 16 + quad * 4 + rg;
            float S1 = red1[rl * 5 + 0] + red1[rl * 5 + 1] + red1[rl * 5 + 2] + red1[rl * 5 + 3];
            float S2 = red2[rl * 5 + 0] + red2[rl * 5 + 1] + red2[rl * 5 + 2] + red2[rl * 5 + 3];
            float mean = S1 * (1.f / 256);
            float rstd = rsqrtf(S2 * (1.f / 256) - mean * mean + 1e-5f);
            int row = row0 + rl;
            if (row < M) {
                #pragma unroll
                for (int j = 0; j < 4; ++j) {
                    int col = wn + j * 16 + lrow;
                    float out = (acc[i][j][rg] - mean) * rstd * gj[j] + bj[j];
                    size_t o = (size_t)row * 256 + col;
                    x[o]  = out;
                    xb[o] = f2bf(out);
                }
            }
        }
}

// ---------------------------------------------------------------------------
// FUSED FFN (monolithic) + 3-deep counted-vmcnt pipeline (T4).
// x = LN2(x + relu(xb@W1+b1)@W2 + b2); also xb, qb outputs.
// 32-row block; hidden in 4 chunks of 256 kept in LDS.
// K-loops: triple-buffered As/Bs; per step: vmcnt(4) [own stage(k) landed,
// stages k+1,k+2 stay in flight] -> raw barrier -> issue stage(k+2) ->
// consume buf[k%3]. stage(k+2) writes buf[(k-1)%3], safe only AFTER
// barrier_k (all waves past consume(k-1)). Last step waits vmcnt(0).
// LDS: As 6K + Bs 48K + Hs 16.5K = 70.5KB -> 2 blocks/CU (= R5 measured
// residency). red aliased onto As[0] (dead by epilogue).
// ---------------------------------------------------------------------------
__global__ __launch_bounds__(256, 2)
void ffn_kernel(const ushort_t* __restrict__ Axb, const ushort_t* __restrict__ W1t,
                const ushort_t* __restrict__ W2t,
                const float* __restrict__ bias1, const float* __restrict__ bias2,
                float* __restrict__ x, ushort_t* __restrict__ xb,
                ushort_t* __restrict__ qb, const ushort_t* __restrict__ posb,
                const float* __restrict__ lng, const float* __restrict__ lnb,
                int M)
{
    __shared__ short As[3][32 * 32];
    __shared__ short Bs[3][256 * 32];
    __shared__ short Hs[32 * 264];
    float* red1 = (float*)&As[0][0];          // aliased; As dead by epilogue
    float* red2 = red1 + 32 * 5;
    const int K = 256;
    int t    = threadIdx.x;
    int row0 = blockIdx.x * 32;
    int lane = t & 63;
    int w    = t >> 6;
    int wn   = w * 64;
    const int quad = lane >> 4, lrow = lane & 15;
    int srow = lane >> 2;
    const int sw = (((lane & 3) ^ ((lane >> 3) & 3)) * 8);
    const int rs = ((quad ^ ((lrow >> 1) & 3)) * 8);

    f32x4 acc[2][4];
    #pragma unroll
    for (int i = 0; i < 2; ++i)
        #pragma unroll
        for (int j = 0; j < 4; ++j)
            acc[i][j] = (f32x4){0.f, 0.f, 0.f, 0.f};

    const ushort_t* Ag = Axb + (size_t)(row0 + w * 16 + srow) * K + sw;  // w<2

    for (int c = 0; c < 4; ++c) {
        f32x4 hh[2][4];
        #pragma unroll
        for (int i = 0; i < 2; ++i)
            #pragma unroll
            for (int j = 0; j < 4; ++j)
                hh[i][j] = (f32x4){0.f, 0.f, 0.f, 0.f};

        // GEMM1: hh = xb[32xK] @ W1t[c*256+: 256 rows][K]^T
        const ushort_t* B1g = W1t + (size_t)(c * 256 + w * 64 + srow) * K + sw;

        __syncthreads();    // prev chunk's GEMM2 done reading Bs (vmcnt==0 here)
        // 3-deep prologue: stage steps 0,1
        #pragma unroll
        for (int s = 0; s < 2; ++s) {
            if (w < 2) gload16(Ag + s * 32, (ushort_t*)&As[s][(w * 16) * 32]);
            #pragma unroll
            for (int q = 0; q < 4; ++q)
                gload16(B1g + (size_t)(q * 16) * K + s * 32,
                        (ushort_t*)&Bs[s][(w * 64 + q * 16) * 32]);
        }

        #pragma unroll
        for (int ks = 0; ks < 8; ++ks) {
            if (ks < 7) { VMCNT4; } else { VMCNT0; }   // own stage(ks) landed
            rawbar();                                   // everyone's stage(ks) landed
            if (ks + 2 < 8) {
                const int nb = (ks + 2) % 3;
                if (w < 2) gload16(Ag + (ks + 2) * 32,
                                   (ushort_t*)&As[nb][(w * 16) * 32]);
                #pragma unroll
                for (int q = 0; q < 4; ++q)
                    gload16(B1g + (size_t)(q * 16) * K + (ks + 2) * 32,
                            (ushort_t*)&Bs[nb][(w * 64 + q * 16) * 32]);
            }
            const int cb = ks % 3;
            bf16x8 af[2], bfr[4];
            #pragma unroll
            for (int i = 0; i < 2; ++i)
                af[i] = *(const bf16x8*)&As[cb][(i * 16 + lrow) * 32 + rs];
            #pragma unroll
            for (int j = 0; j < 4; ++j)
                bfr[j] = *(const bf16x8*)&Bs[cb][(wn + j * 16 + lrow) * 32 + rs];
            #pragma unroll
            for (int i = 0; i < 2; ++i)
                #pragma unroll
                for (int j = 0; j < 4; ++j)
                    hh[i][j] = __builtin_amdgcn_mfma_f32_16x16x32_bf16(af[i], bfr[j], hh[i][j], 0, 0, 0);
        }

        // hidden chunk -> LDS (bias + relu, bf16)
        #pragma unroll
        for (int j = 0; j < 4; ++j) {
            int col = wn + j * 16 + lrow;
            float b1v = bias1[c * 256 + col];
            #pragma unroll
            for (int i = 0; i < 2; ++i)
                #pragma unroll
                for (int rg = 0; rg < 4; ++rg) {
                    int rl = i * 16 + quad * 4 + rg;
                    Hs[rl * 264 + col] = f2bf(fmaxf(hh[i][j][rg] + b1v, 0.f));
                }
        }
        __syncthreads();    // Hs ready; all GEMM1 consumers done (vmcnt==0)

        // GEMM2: acc += Hs[32x256] @ W2t[:, c*256+..]^T  (W2t: [256][1024])
        const ushort_t* B2g = W2t + (size_t)(w * 64 + srow) * 1024 + c * 256 + sw;
        #pragma unroll
        for (int s = 0; s < 2; ++s)
            #pragma unroll
            for (int q = 0; q < 4; ++q)
                gload16(B2g + (size_t)(q * 16) * 1024 + s * 32,
                        (ushort_t*)&Bs[s][(w * 64 + q * 16) * 32]);

        #pragma unroll
        for (int ks = 0; ks < 8; ++ks) {
            if (ks < 7) { VMCNT4; } else { VMCNT0; }
            rawbar();
            if (ks + 2 < 8) {
                const int nb = (ks + 2) % 3;
                #pragma unroll
                for (int q = 0; q < 4; ++q)
                    gload16(B2g + (size_t)(q * 16) * 1024 + (ks + 2) * 32,
                            (ushort_t*)&Bs[nb][(w * 64 + q * 16) * 32]);
            }
            const int cb = ks % 3;
            bf16x8 af[2], bfr[4];
            #pragma unroll
            for (int i = 0; i < 2; ++i)
                af[i] = *(const bf16x8*)&Hs[(i * 16 + lrow) * 264 + ks * 32 + quad * 8];
            #pragma unroll
            for (int j = 0; j < 4; ++j)
                bfr[j] = *(const bf16x8*)&Bs[cb][(wn + j * 16 + lrow) * 32 + rs];
            #pragma unroll
            for (int i = 0; i < 2; ++i)
                #pragma unroll
                for (int j = 0; j < 4; ++j)
                    acc[i][j] = __builtin_amdgcn_mfma_f32_16x16x32_bf16(af[i], bfr[j], acc[i][j], 0, 0, 0);
        }
    }

    // ---- fused epilogue: v = x + (y + bias2); LN2; write x, xb, qb ----
    float gj[4], bj[4], bi[4];
    #pragma unroll
    for (int j = 0; j < 4; ++j) {
        int col = wn + j * 16 + lrow;
        gj[j] = lng[col];
        bj[j] = lnb[col];
        bi[j] = bias2[col];
    }

    #pragma unroll
    for (int i = 0; i < 2; ++i)
        #pragma unroll
        for (int rg = 0; rg < 4; ++rg) {
            int row = row0 + i * 16 + quad * 4 + rg;
            #pragma unroll
            for (int j = 0; j < 4; ++j) {
                int col = wn + j * 16 + lrow;
                float xres = (row < M) ? x[(size_t)row * 256 + col] : 0.f;
                acc[i][j][rg] += bi[j] + xres;
            }
            float p1 = acc[i][0][rg] + acc[i][1][rg] + acc[i][2][rg] + acc[i][3][rg];
            float p2 = acc[i][0][rg] * acc[i][0][rg] + acc[i][1][rg] * acc[i][1][rg]
                     + acc[i][2][rg] * acc[i][2][rg] + acc[i][3][rg] * acc[i][3][rg];
            p1 += __shfl_xor(p1, 1); p2 += __shfl_xor(p2, 1);
            p1 += __shfl_xor(p1, 2); p2 += __shfl_xor(p2, 2);
            p1 += __shfl_xor(p1, 4); p2 += __shfl_xor(p2, 4);
            p1 += __shfl_xor(p1, 8); p2 += __shfl_xor(p2, 8);
            if (lrow == 0) {
                int rl = i * 16 + quad * 4 + rg;
                red1[rl * 5 + w] = p1;
                red2[rl * 5 + w] = p2;
            }
        }
    __syncthreads();

    #pragma unroll
    for (int i = 0; i < 2; ++i)
        #pragma unroll
        for (int rg = 0; rg < 4; ++rg) {
            int rl = i * 16 + quad * 4 + rg;
            float S1 = red1[rl * 5 + 0] + red1[rl * 5 + 1] + red1[rl * 5 + 2] + red1[rl * 5 + 3];
            float S2 = red2[rl * 5 + 0] + red2[rl * 5 + 1] + red2[rl * 5 + 2] + red2[rl * 5 + 3];
            float mean = S1 * (1.f / 256);
            float rstd = rsqrtf(S2 * (1.f / 256) - mean * mean + 1e-5f);
            int row = row0 + rl;
            if (row < M) {
                #pragma unroll
                for (int j = 0; j < 4; ++j) {
                    int col = wn + j * 16 + lrow;
                    float out = (acc[i][j][rg] - mean) * rstd * gj[j] + bj[j];
                    size_t o = (size_t)row * 256 + col;
                    x[o]  = out;
                    xb[o] = f2bf(out);
                    qb[o] = f2bf(out + bf2f(posb[o]));
                }
            }
        }
}

// ---------------------------------------------------------------------------
// Fused deformable sampling, v7: XCD-pinned heads + 16B-lane gathers +
// relaxed VGPR cap for deep load pipelining.
// ---------------------------------------------------------------------------
__global__ __launch_bounds__(256, 4)
void sample_kernel(const ushort_t* __restrict__ valueb,
                   const ushort_t* __restrict__ offh,   // [NH][M][48]
                   const ushort_t* __restrict__ attnh,  // [NH][M][16]
                   ushort_t* __restrict__ sampb)
{
    __shared__ float wrec[16 * 168];
    __shared__ int   idxA[16 * 40];

    const int LD_[4]  = {4, 2, 1, 1};
    const int LH_[4]  = {48, 24, 12, 6};
    const int LW_[4]  = {48, 24, 12, 6};
    const int LS0_[4] = {0, 9216, 10368, 10512};

    int t   = threadIdx.x;
    int gl  = t >> 4;                   // local group 0..15
    int sub = t & 15;
    int h   = blockIdx.x;
    int r   = blockIdx.y * 16 + gl;
    bool valid = (r < M_ROWS);
    if (!valid) r = M_ROWS - 1;
    int b   = (r >= S_TOT) ? 1 : 0;
    int s   = r - b * S_TOT;

    float rx, ry, rz;
    {
        int j;
        if (s < 9216)       { j = s;         int qx = j % 48; int q2 = j / 48; int qy = q2 % 48; int qz = q2 / 48;
                              rx = (qx + 0.5f) * (1.f/48); ry = (qy + 0.5f) * (1.f/48); rz = (qz + 0.5f) * (1.f/4); }
        else if (s < 10368) { j = s - 9216;  int qx = j % 24; int q2 = j / 24; int qy = q2 % 24; int qz = q2 / 24;
                              rx = (qx + 0.5f) * (1.f/24); ry = (qy + 0.5f) * (1.f/24); rz = (qz + 0.5f) * (1.f/2); }
        else if (s < 10512) { j = s - 10368; int qx = j % 12; int qy = j / 12;
                              rx = (qx + 0.5f) * (1.f/12); ry = (qy + 0.5f) * (1.f/12); rz = 0.5f; }
        else                { j = s - 10512; int qx = j % 6;  int qy = j / 6;
                              rx = (qx + 0.5f) * (1.f/6);  ry = (qy + 0.5f) * (1.f/6);  rz = 0.5f; }
    }

    // ---- phase 1: one point per lane ----
    {
        int p = sub;
        float lg = bf2f(attnh[((size_t)h * M_ROWS + r) * 16 + p]);
        float mx = lg;
        mx = fmaxf(mx, __shfl_xor(mx, 1));
        mx = fmaxf(mx, __shfl_xor(mx, 2));
        mx = fmaxf(mx, __shfl_xor(mx, 4));
        mx = fmaxf(mx, __shfl_xor(mx, 8));
        float e = __expf(lg - mx);
        float sm = e;
        sm += __shfl_xor(sm, 1);
        sm += __shfl_xor(sm, 2);
        sm += __shfl_xor(sm, 4);
        sm += __shfl_xor(sm, 8);
        float aw = e / sm;

        int lvl = p >> 2;
        const int Dl = LD_[lvl], Hl = LH_[lvl], Wl = LW_[lvl];
        size_t base3 = ((size_t)h * M_ROWS + r) * 48 + p * 3;
        float cx = rx * Wl + bf2f(offh[base3 + 0]) - 0.5f;
        float cy = ry * Hl + bf2f(offh[base3 + 1]) - 0.5f;
        float cz = rz * Dl + bf2f(offh[base3 + 2]) - 0.5f;
        float xf = floorf(cx), yf = floorf(cy), zf = floorf(cz);
        float fx = cx - xf, fy = cy - yf, fz = cz - zf;
        int x0 = (int)xf, y0 = (int)yf, z0 = (int)zf;
        float wx0 = ((unsigned)x0       < (unsigned)Wl) ? 1.f - fx : 0.f;
        float wx1 = ((unsigned)(x0 + 1) < (unsigned)Wl) ? fx       : 0.f;
        float wy0 = ((unsigned)y0       < (unsigned)Hl) ? 1.f - fy : 0.f;
        float wy1 = ((unsigned)(y0 + 1) < (unsigned)Hl) ? fy       : 0.f;
        float wz0 = ((unsigned)z0       < (unsigned)Dl) ? (1.f - fz) * aw : 0.f;
        float wz1 = ((unsigned)(z0 + 1) < (unsigned)Dl) ? fz * aw       : 0.f;
        int xc = min(max(x0, -1), Wl - 1);
        int yc = min(max(y0, -1), Hl - 1);
        int zc = min(max(z0, -1), Dl - 1);
        int idx = LS0_[lvl] + (zc * Hl + yc) * Wl + xc;

        float* wp = &wrec[gl * 168 + p * 8];
        *(f32x4*)wp       = (f32x4){wz0 * wy0 * wx0, wz0 * wy0 * wx1,
                                    wz0 * wy1 * wx0, wz0 * wy1 * wx1};
        *(f32x4*)(wp + 4) = (f32x4){wz1 * wy0 * wx0, wz1 * wy0 * wx1,
                                    wz1 * wy1 * wx0, wz1 * wy1 * wx1};
        idxA[gl * 40 + p] = idx;
    }
    __syncthreads();

    // ---- phase 2: corner cr = (dy,dx), channel octet q ----
    int q  = sub & 3;
    int cr = sub >> 2;
    int dy = cr >> 1, dx = cr & 1;
    const ushort_t* vb = valueb + ((size_t)(b * NH_DIM + h) * S_TOT) * HD_DIM + q * 8;
    f32x4 accA = (f32x4){0.f, 0.f, 0.f, 0.f};
    f32x4 accB = (f32x4){0.f, 0.f, 0.f, 0.f};

    #pragma unroll
    for (int p = 0; p < 16; ++p) {
        const int lvl = p >> 2;
        const int Wl = LW_[lvl];
        const int HW = LH_[lvl] * LW_[lvl];
        float w0 = wrec[gl * 168 + p * 8 + cr];
        float w1 = wrec[gl * 168 + p * 8 + 4 + cr];
        int idx = idxA[gl * 40 + p] + dy * Wl + dx;
        const ushort_t* cb = vb + (long long)idx * HD_DIM;
        uint4 u0 = *(const uint4*)cb;
        uint4 u1 = *(const uint4*)(cb + HW * HD_DIM);
        accA += w0 * up2(u0.x, u0.y);
        accB += w0 * up2(u0.z, u0.w);
        accA += w1 * up2(u1.x, u1.y);
        accB += w1 * up2(u1.z, u1.w);
    }

    accA.x += __shfl_xor(accA.x, 4); accA.y += __shfl_xor(accA.y, 4);
    accA.z += __shfl_xor(accA.z, 4); accA.w += __shfl_xor(accA.w, 4);
    accB.x += __shfl_xor(accB.x, 4); accB.y += __shfl_xor(accB.y, 4);
    accB.z += __shfl_xor(accB.z, 4); accB.w += __shfl_xor(accB.w, 4);
    accA.x += __shfl_xor(accA.x, 8); accA.y += __shfl_xor(accA.y, 8);
    accA.z += __shfl_xor(accA.z, 8); accA.w += __shfl_xor(accA.w, 8);
    accB.x += __shfl_xor(accB.x, 8); accB.y += __shfl_xor(accB.y, 8);
    accB.z += __shfl_xor(accB.z, 8); accB.w += __shfl_xor(accB.w, 8);

    if (cr == 0 && valid) {
        ushort4 o1, o2;
        o1.x = f2bf(accA.x); o1.y = f2bf(accA.y); o1.z = f2bf(accA.z); o1.w = f2bf(accA.w);
        o2.x = f2bf(accB.x); o2.y = f2bf(accB.y); o2.z = f2bf(accB.z); o2.w = f2bf(accB.w);
        ushort_t* op = sampb + (size_t)r * E_DIM + h * HD_DIM + q * 8;
        *(ushort4*)op       = o1;
        *(ushort4*)(op + 4) = o2;
    }
}

// ---------------------------------------------------------------------------
extern "C" void kernel_launch(void* const* d_in, const int* in_sizes, int n_in,
                              void* d_out, int out_size, void* d_ws, size_t ws_size,
                              hipStream_t stream)
{
    const float* f0     = (const float*)d_in[0];
    const float* p0     = (const float*)d_in[1];
    const float* f1     = (const float*)d_in[2];
    const float* p1     = (const float*)d_in[3];
    const float* f2     = (const float*)d_in[4];
    const float* p2     = (const float*)d_in[5];
    const float* f3     = (const float*)d_in[6];
    const float* p3     = (const float*)d_in[7];
    const float* lemb   = (const float*)d_in[8];
    const float* W_off  = (const float*)d_in[9];
    const float* b_off  = (const float*)d_in[10];
    const float* W_attn = (const float*)d_in[11];
    const float* b_attn = (const float*)d_in[12];
    const float* W_val  = (const float*)d_in[13];
    const float* b_val  = (const float*)d_in[14];
    const float* W_out  = (const float*)d_in[15];
    const float* b_out  = (const float*)d_in[16];
    const float* ln1_g  = (const float*)d_in[17];
    const float* ln1_b  = (const float*)d_in[18];
    const float* W_ff1  = (const float*)d_in[19];
    const float* b_ff1  = (const float*)d_in[20];
    const float* W_ff2  = (const float*)d_in[21];
    const float* b_ff2  = (const float*)d_in[22];
    const float* ln2_g  = (const float*)d_in[23];
    const float* ln2_b  = (const float*)d_in[24];

    float* x = (float*)d_out;
    char*  w = (char*)d_ws;

    // ws layout (bytes)
    ushort_t* posb   = (ushort_t*)(w + 0);                   // 10,813,440
    // value region: 256KB front guard | (B,NH,S,HD) bf16 | 128KB back guard
    ushort_t* valueb = (ushort_t*)(w + 21626880 + 262144);
    char*     region =            (w + 34525184);            // 43,253,760
    ushort_t* offh   = (ushort_t*)(region);                  // [NH][M][48] 16,220,160
    ushort_t* attnh  = (ushort_t*)(region + 16220160);       // [NH][M][16]  5,406,720
    ushort_t* sampb  = (ushort_t*)(region + 21626880);       // 10,813,440
    ushort_t* xb     = (ushort_t*)(w + 77778944);            // 10,813,440
    ushort_t* qb     = (ushort_t*)(w + 88592384);            // 10,813,440
    ushort_t* wb     = (ushort_t*)(w + 99405824);            //  9,437,184

    // Combined attention weight: per layer 768 rows x 256 K
    ushort_t* Wc_t = wb;              // [6][768][256]
    ushort_t* Wp_t = wb + 1179648;    // [6][256][256]
    ushort_t* W1_t = wb + 1572864;    // [6][1024][256]
    ushort_t* W2_t = wb + 3145728;    // [6][256][1024]

    dim3 blk(256);

    transpose_cvt_kernel<<<dim3(8, 8, 6),  blk, 0, stream>>>(W_val,  Wc_t, 256, 256,  196608, 0);
    transpose_cvt_kernel<<<dim3(12, 8, 6), blk, 0, stream>>>(W_off,  Wc_t, 256, 384,  196608, 256);
    transpose_cvt_kernel<<<dim3(4, 8, 6),  blk, 0, stream>>>(W_attn, Wc_t, 256, 128,  196608, 640);
    transpose_cvt_kernel<<<dim3(8, 8, 6),  blk, 0, stream>>>(W_out,  Wp_t, 256, 256,   65536, 0);
    transpose_cvt_kernel<<<dim3(32, 8, 6), blk, 0, stream>>>(W_ff1,  W1_t, 256, 1024, 262144, 0);
    transpose_cvt_kernel<<<dim3(8, 32, 6), blk, 0, stream>>>(W_ff2,  W2_t, 1024, 256, 262144, 0);

    // 331 j-tiles (288+36+5+2), 8 e-tiles, 2 batches
    assemble_kernel<<<dim3(331, 8, 2), blk, 0, stream>>>(
        f0, p0, f1, p1, f2, p2, f3, p3, lemb, x, posb, xb, qb);

    const int MT = M_PAD / 64;               // 330 (part1 grid.y)
    const int LT = M_PAD / 32;               // 660 (gemm_ln / ffn grids)
    const int SB = (M_ROWS + 15) / 16;       // 1319
    for (int l = 0; l < NLAYERS; ++l) {
        gemm_part1<<<dim3(3, MT), blk, 0, stream>>>(
            xb, qb, Wc_t + l * 196608,
            b_val + l * 256, b_off + l * 384, b_attn + l * 128,
            valueb, offh, attnh, M_ROWS);
        sample_kernel<<<dim3(NH_DIM, SB), blk, 0, stream>>>(valueb, offh, attnh, sampb);
        gemm_ln<<<LT, blk, 0, stream>>>(
            sampb, Wp_t + l * 65536, b_out + l * 256,
            x, xb, ln1_g + l * 256, ln1_b + l * 256, M_ROWS);
        ffn_kernel<<<LT, blk, 0, stream>>>(
            xb, W1_t + l * 262144, W2_t + l * 262144,
            b_ff1 + l * 1024, b_ff2 + l * 256,
            x, xb, qb, posb,
            ln2_g + l * 256, ln2_b + l * 256, M_ROWS);
    }
}

// Round 12
// 1111.004 us; speedup vs baseline: 1.1670x; 1.1348x over previous
//
#include <hip/hip_runtime.h>

#define S_TOT   10548
#define M_ROWS  21096
#define M_PAD   21120          // 330*64 = 660*32
#define E_DIM   256
#define NH_DIM  8
#define HD_DIM  32
#define DF_DIM  1024
#define NLAYERS 6

typedef unsigned short ushort_t;
typedef __attribute__((ext_vector_type(8))) short bf16x8;
typedef __attribute__((ext_vector_type(4))) float f32x4;

__device__ inline ushort_t f2bf(float f) {
    unsigned u = __float_as_uint(f);
    u += 0x7FFF + ((u >> 16) & 1);          // RNE
    return (ushort_t)(u >> 16);
}
__device__ inline float bf2f(ushort_t h) {
    return __uint_as_float(((unsigned)h) << 16);
}
__device__ inline f32x4 up2(unsigned a, unsigned b) {
    f32x4 v;
    v.x = __uint_as_float(a << 16);
    v.y = __uint_as_float(a & 0xffff0000u);
    v.z = __uint_as_float(b << 16);
    v.w = __uint_as_float(b & 0xffff0000u);
    return v;
}
// async global->LDS, 16B per lane; LDS dest wave-uniform, lane scatters at
// dest + lane*16.
__device__ inline void gload16(const ushort_t* g, ushort_t* l) {
    __builtin_amdgcn_global_load_lds(
        (const __attribute__((address_space(1))) void*)g,
        (__attribute__((address_space(3))) void*)l, 16, 0, 0);
}

// ---------------------------------------------------------------------------
// Input assembly v2: LDS-transpose tiles, both sides coalesced.
// grid = (331 j-tiles, 8 e-tiles, 2 batches).
// ---------------------------------------------------------------------------
__global__ __launch_bounds__(256)
void assemble_kernel(const float* __restrict__ f0, const float* __restrict__ p0,
                     const float* __restrict__ f1, const float* __restrict__ p1,
                     const float* __restrict__ f2, const float* __restrict__ p2,
                     const float* __restrict__ f3, const float* __restrict__ p3,
                     const float* __restrict__ lemb,
                     float* __restrict__ x, ushort_t* __restrict__ posb,
                     ushort_t* __restrict__ xb, ushort_t* __restrict__ qb)
{
    __shared__ float tf[32][33];
    __shared__ float tp[32][33];

    int tb = blockIdx.x;
    int e0 = blockIdx.y * 32;
    int b  = blockIdx.z;
    int lvl, j0, n, s0; const float* f; const float* p;
    if (tb < 288)      { lvl = 0; j0 = tb * 32;         n = 9216; s0 = 0;     f = f0; p = p0; }
    else if (tb < 324) { lvl = 1; j0 = (tb - 288) * 32; n = 1152; s0 = 9216;  f = f1; p = p1; }
    else if (tb < 329) { lvl = 2; j0 = (tb - 324) * 32; n = 144;  s0 = 10368; f = f2; p = p2; }
    else               { lvl = 3; j0 = (tb - 329) * 32; n = 36;   s0 = 10512; f = f3; p = p3; }

    int tx = threadIdx.x & 31, ty = threadIdx.x >> 5;
    bool jv = (j0 + tx) < n;
    size_t base = (size_t)(b * E_DIM + e0) * n + j0 + tx;
    #pragma unroll
    for (int i = 0; i < 4; ++i) {
        int e = ty + i * 8;
        float fv = 0.f, pv = 0.f;
        if (jv) {
            fv = f[base + (size_t)e * n];
            pv = p[base + (size_t)e * n];
        }
        tf[e][tx] = fv;
        tp[e][tx] = pv;
    }
    __syncthreads();

    float lv = lemb[lvl * E_DIM + e0 + tx];
    #pragma unroll
    for (int i = 0; i < 4; ++i) {
        int jl = ty + i * 8;
        if (j0 + jl < n) {
            int r = b * S_TOT + s0 + j0 + jl;
            float xv = tf[tx][jl];
            float pv = tp[tx][jl] + lv;
            size_t o = (size_t)r * E_DIM + e0 + tx;
            x[o]    = xv;
            posb[o] = f2bf(pv);
            xb[o]   = f2bf(xv);
            qb[o]   = f2bf(xv + pv);
        }
    }
}

// ---------------------------------------------------------------------------
// Weight convert+transpose: src f32 [L,K,N] -> dst bf16 [L(stride), rowOff+N, K]
// ---------------------------------------------------------------------------
__global__ __launch_bounds__(256)
void transpose_cvt_kernel(const float* __restrict__ src, ushort_t* __restrict__ dst,
                          int K, int N, int dstLayerStride, int dstRowOff)
{
    __shared__ float tile[32][33];
    int l  = blockIdx.z;
    int n0 = blockIdx.x * 32, k0 = blockIdx.y * 32;
    int tx = threadIdx.x & 31, ty = threadIdx.x >> 5;
    const float* s = src + (size_t)l * K * N;
    ushort_t* d    = dst + (size_t)l * dstLayerStride + (size_t)dstRowOff * K;
    #pragma unroll
    for (int i = 0; i < 32; i += 8)
        tile[ty + i][tx] = s[(size_t)(k0 + ty + i) * N + n0 + tx];
    __syncthreads();
    #pragma unroll
    for (int i = 0; i < 32; i += 8)
        d[(size_t)(n0 + ty + i) * K + k0 + tx] = f2bf(tile[tx][ty + i]);
}

// ---------------------------------------------------------------------------
// 64x256-tile bf16 MFMA GEMM (part1), double-buffered single-sync K-loop.
// grid.x=sup: 0=value (A=xb, permute store), 1=off[0:256),
// 2=off[256:384)+attn (A=qb); off/attn stored HEAD-MAJOR.
// (256,4): LDS 40KB allows 4 blocks/CU; VGPR ~116 fits the 128 cap.
// ---------------------------------------------------------------------------
__global__ __launch_bounds__(256, 4)
void gemm_part1(const ushort_t* __restrict__ A0, const ushort_t* __restrict__ A1,
                const ushort_t* __restrict__ BtBase,
                const float* __restrict__ b1, const float* __restrict__ b2,
                const float* __restrict__ b3,
                ushort_t* __restrict__ O1, ushort_t* __restrict__ O2,
                ushort_t* __restrict__ O3, int M)
{
    __shared__ short As[2][64 * 32];
    __shared__ short Bs[2][256 * 32];
    const int K = 256;
    int t    = threadIdx.x;
    int sup  = blockIdx.x;
    int row0 = blockIdx.y * 64;
    int lane = t & 63;
    int w    = t >> 6;
    int wn   = w * 64;
    const int quad = lane >> 4, lrow = lane & 15;

    const ushort_t* A  = (sup != 0) ? A1 : A0;
    const ushort_t* Bt = BtBase + (size_t)sup * 256 * K;

    f32x4 acc[4][4];
    #pragma unroll
    for (int i = 0; i < 4; ++i)
        #pragma unroll
        for (int j = 0; j < 4; ++j)
            acc[i][j] = (f32x4){0.f, 0.f, 0.f, 0.f};

    int srow = lane >> 2;
    const int sw = (((lane & 3) ^ ((lane >> 3) & 3)) * 8);     // swizzled k-seg
    const int rs = ((quad ^ ((lrow >> 1) & 3)) * 8);           // fragment slot
    const ushort_t* Ag = A + (size_t)(row0 + w * 16 + srow) * K + sw;
    const ushort_t* Bg = Bt + (size_t)(w * 64 + srow) * K + sw;

    // prologue: stage k0=0 into buffer 0
    gload16(Ag, (ushort_t*)&As[0][(w * 16) * 32]);
    #pragma unroll
    for (int q = 0; q < 4; ++q)
        gload16(Bg + (size_t)(q * 16) * K,
                (ushort_t*)&Bs[0][(w * 64 + q * 16) * 32]);

    #pragma unroll
    for (int k0 = 0; k0 < K; k0 += 32) {
        const int cur = (k0 >> 5) & 1;
        __syncthreads();                      // stage(k) landed; buf cur^1 free
        if (k0 + 32 < K) {
            const int nxt = cur ^ 1;
            gload16(Ag + k0 + 32, (ushort_t*)&As[nxt][(w * 16) * 32]);
            #pragma unroll
            for (int q = 0; q < 4; ++q)
                gload16(Bg + (size_t)(q * 16) * K + k0 + 32,
                        (ushort_t*)&Bs[nxt][(w * 64 + q * 16) * 32]);
        }
        bf16x8 af[4], bfr[4];
        #pragma unroll
        for (int i = 0; i < 4; ++i)
            af[i] = *(const bf16x8*)&As[cur][(i * 16 + lrow) * 32 + rs];
        #pragma unroll
        for (int j = 0; j < 4; ++j)
            bfr[j] = *(const bf16x8*)&Bs[cur][(wn + j * 16 + lrow) * 32 + rs];
        #pragma unroll
        for (int i = 0; i < 4; ++i)
            #pragma unroll
            for (int j = 0; j < 4; ++j)
                acc[i][j] = __builtin_amdgcn_mfma_f32_16x16x32_bf16(af[i], bfr[j], acc[i][j], 0, 0, 0);
    }

    #pragma unroll
    for (int j = 0; j < 4; ++j) {
        int col = wn + j * 16 + lrow;     // 0..255 local
        float bia = (sup == 0) ? b1[col]
                  : (sup == 1) ? b2[col]
                  : (col < 128) ? b2[256 + col] : b3[col - 128];
        #pragma unroll
        for (int i = 0; i < 4; ++i)
            #pragma unroll
            for (int rg = 0; rg < 4; ++rg) {
                int row = row0 + i * 16 + quad * 4 + rg;
                if (row < M) {
                    float v = acc[i][j][rg] + bia;
                    if (sup == 0) {
                        int b = (row >= S_TOT) ? 1 : 0;
                        int s = row - b * S_TOT;
                        O1[(((size_t)(b * NH_DIM + (col >> 5))) * S_TOT + s) * HD_DIM + (col & 31)] = f2bf(v);
                    } else if (sup == 2 && col >= 128) {
                        int acol = col - 128;
                        O3[((size_t)(acol >> 4) * M_ROWS + row) * 16 + (acol & 15)] = f2bf(v);
                    } else {
                        int ocol = (sup == 1) ? col : 256 + col;
                        int hh = (ocol * 1366) >> 16;            // /48
                        O2[((size_t)hh * M_ROWS + row) * 48 + (ocol - hh * 48)] = f2bf(v);
                    }
                }
            }
    }
}

// ---------------------------------------------------------------------------
// 32x256-tile bf16 MFMA GEMM + FUSED residual + LayerNorm epilogue (out-proj).
// Double-buffered single-sync K-loop; red scratch aliased onto As[0].
// LDS 36KB -> 4 blocks/CU.
// ---------------------------------------------------------------------------
__global__ __launch_bounds__(256, 4)
void gemm_ln(const ushort_t* __restrict__ A, const ushort_t* __restrict__ Bt,
             const float* __restrict__ bias,
             float* __restrict__ x, ushort_t* __restrict__ xb,
             const float* __restrict__ lng, const float* __restrict__ lnb,
             int M)
{
    __shared__ short As[2][32 * 32];
    __shared__ short Bs[2][256 * 32];
    float* red1 = (float*)&As[0][0];          // 160 floats
    float* red2 = red1 + 32 * 5;              // 160 floats (1280B <= 2048B)
    const int K = 256;
    int t    = threadIdx.x;
    int row0 = blockIdx.x * 32;
    int lane = t & 63;
    int w    = t >> 6;
    int wn   = w * 64;
    const int quad = lane >> 4, lrow = lane & 15;

    f32x4 acc[2][4];
    #pragma unroll
    for (int i = 0; i < 2; ++i)
        #pragma unroll
        for (int j = 0; j < 4; ++j)
            acc[i][j] = (f32x4){0.f, 0.f, 0.f, 0.f};

    int srow = lane >> 2;
    const int sw = (((lane & 3) ^ ((lane >> 3) & 3)) * 8);
    const int rs = ((quad ^ ((lrow >> 1) & 3)) * 8);
    const ushort_t* Ag = A + (size_t)(row0 + w * 16 + srow) * K + sw;   // w<2
    const ushort_t* Bg = Bt + (size_t)(w * 64 + srow) * K + sw;

    if (w < 2) gload16(Ag, (ushort_t*)&As[0][(w * 16) * 32]);
    #pragma unroll
    for (int q = 0; q < 4; ++q)
        gload16(Bg + (size_t)(q * 16) * K,
                (ushort_t*)&Bs[0][(w * 64 + q * 16) * 32]);

    #pragma unroll
    for (int k0 = 0; k0 < K; k0 += 32) {
        const int cur = (k0 >> 5) & 1;
        __syncthreads();
        if (k0 + 32 < K) {
            const int nxt = cur ^ 1;
            if (w < 2) gload16(Ag + k0 + 32, (ushort_t*)&As[nxt][(w * 16) * 32]);
            #pragma unroll
            for (int q = 0; q < 4; ++q)
                gload16(Bg + (size_t)(q * 16) * K + k0 + 32,
                        (ushort_t*)&Bs[nxt][(w * 64 + q * 16) * 32]);
        }
        bf16x8 af[2], bfr[4];
        #pragma unroll
        for (int i = 0; i < 2; ++i)
            af[i] = *(const bf16x8*)&As[cur][(i * 16 + lrow) * 32 + rs];
        #pragma unroll
        for (int j = 0; j < 4; ++j)
            bfr[j] = *(const bf16x8*)&Bs[cur][(wn + j * 16 + lrow) * 32 + rs];
        #pragma unroll
        for (int i = 0; i < 2; ++i)
            #pragma unroll
            for (int j = 0; j < 4; ++j)
                acc[i][j] = __builtin_amdgcn_mfma_f32_16x16x32_bf16(af[i], bfr[j], acc[i][j], 0, 0, 0);
    }

    // ---- fused epilogue: v = x + (y + bias); LayerNorm per row ----
    float gj[4], bj[4], bi[4];
    #pragma unroll
    for (int j = 0; j < 4; ++j) {
        int col = wn + j * 16 + lrow;
        gj[j] = lng[col];
        bj[j] = lnb[col];
        bi[j] = bias[col];
    }

    #pragma unroll
    for (int i = 0; i < 2; ++i)
        #pragma unroll
        for (int rg = 0; rg < 4; ++rg) {
            int row = row0 + i * 16 + quad * 4 + rg;
            #pragma unroll
            for (int j = 0; j < 4; ++j) {
                int col = wn + j * 16 + lrow;
                float xres = (row < M) ? x[(size_t)row * 256 + col] : 0.f;
                acc[i][j][rg] += bi[j] + xres;
            }
            float p1 = acc[i][0][rg] + acc[i][1][rg] + acc[i][2][rg] + acc[i][3][rg];
            float p2 = acc[i][0][rg] * acc[i][0][rg] + acc[i][1][rg] * acc[i][1][rg]
                     + acc[i][2][rg] * acc[i][2][rg] + acc[i][3][rg] * acc[i][3][rg];
            p1 += __shfl_xor(p1, 1); p2 += __shfl_xor(p2, 1);
            p1 += __shfl_xor(p1, 2); p2 += __shfl_xor(p2, 2);
            p1 += __shfl_xor(p1, 4); p2 += __shfl_xor(p2, 4);
            p1 += __shfl_xor(p1, 8); p2 += __shfl_xor(p2, 8);
            if (lrow == 0) {
                int rl = i * 16 + quad * 4 + rg;
                red1[rl * 5 + w] = p1;
                red2[rl * 5 + w] = p2;
            }
        }
    __syncthreads();

    #pragma unroll
    for (int i = 0; i < 2; ++i)
        #pragma unroll
        for (int rg = 0; rg < 4; ++rg) {
            int rl = i * 16 + quad * 4 + rg;
            float S1 = red1[rl * 5 + 0] + red1[rl * 5 + 1] + red1[rl * 5 + 2] + red1[rl * 5 + 3];
            float S2 = red2[rl * 5 + 0] + red2[rl * 5 + 1] + red2[rl * 5 + 2] + red2[rl * 5 + 3];
            float mean = S1 * (1.f / 256);
            float rstd = rsqrtf(S2 * (1.f / 256) - mean * mean + 1e-5f);
            int row = row0 + rl;
            if (row < M) {
                #pragma unroll
                for (int j = 0; j < 4; ++j) {
                    int col = wn + j * 16 + lrow;
                    float out = (acc[i][j][rg] - mean) * rstd * gj[j] + bj[j];
                    size_t o = (size_t)row * 256 + col;
                    x[o]  = out;
                    xb[o] = f2bf(out);
                }
            }
        }
}

// ---------------------------------------------------------------------------
// FUSED FFN (exact R5 measured-best): x = LN2(x + relu(xb@W1+b1)@W2 + b2);
// also xb, qb outputs. 32-row block; hidden in 4 chunks of 256, kept in LDS.
// Double-buffered single-sync K-loops; red aliased onto As[0].
// LDS 52.5KB. Measured 67 us/dispatch, VGPR 76.
// ---------------------------------------------------------------------------
__global__ __launch_bounds__(256, 2)
void ffn_kernel(const ushort_t* __restrict__ Axb, const ushort_t* __restrict__ W1t,
                const ushort_t* __restrict__ W2t,
                const float* __restrict__ bias1, const float* __restrict__ bias2,
                float* __restrict__ x, ushort_t* __restrict__ xb,
                ushort_t* __restrict__ qb, const ushort_t* __restrict__ posb,
                const float* __restrict__ lng, const float* __restrict__ lnb,
                int M)
{
    __shared__ short As[2][32 * 32];
    __shared__ short Bs[2][256 * 32];
    __shared__ short Hs[32 * 264];
    float* red1 = (float*)&As[0][0];          // aliased; safe (see gemm_ln)
    float* red2 = red1 + 32 * 5;
    const int K = 256;
    int t    = threadIdx.x;
    int row0 = blockIdx.x * 32;
    int lane = t & 63;
    int w    = t >> 6;
    int wn   = w * 64;
    const int quad = lane >> 4, lrow = lane & 15;
    int srow = lane >> 2;
    const int sw = (((lane & 3) ^ ((lane >> 3) & 3)) * 8);
    const int rs = ((quad ^ ((lrow >> 1) & 3)) * 8);

    f32x4 acc[2][4];
    #pragma unroll
    for (int i = 0; i < 2; ++i)
        #pragma unroll
        for (int j = 0; j < 4; ++j)
            acc[i][j] = (f32x4){0.f, 0.f, 0.f, 0.f};

    const ushort_t* Ag = Axb + (size_t)(row0 + w * 16 + srow) * K + sw;  // w<2

    for (int c = 0; c < 4; ++c) {
        f32x4 hh[2][4];
        #pragma unroll
        for (int i = 0; i < 2; ++i)
            #pragma unroll
            for (int j = 0; j < 4; ++j)
                hh[i][j] = (f32x4){0.f, 0.f, 0.f, 0.f};

        // GEMM1: hh = xb[32xK] @ W1t[c*256+: 256 rows][K]^T
        const ushort_t* B1g = W1t + (size_t)(c * 256 + w * 64 + srow) * K + sw;

        __syncthreads();    // prev chunk's GEMM2 done reading Bs
        if (w < 2) gload16(Ag, (ushort_t*)&As[0][(w * 16) * 32]);
        #pragma unroll
        for (int q = 0; q < 4; ++q)
            gload16(B1g + (size_t)(q * 16) * K,
                    (ushort_t*)&Bs[0][(w * 64 + q * 16) * 32]);

        #pragma unroll
        for (int k0 = 0; k0 < K; k0 += 32) {
            const int cur = (k0 >> 5) & 1;
            __syncthreads();
            if (k0 + 32 < K) {
                const int nxt = cur ^ 1;
                if (w < 2) gload16(Ag + k0 + 32, (ushort_t*)&As[nxt][(w * 16) * 32]);
                #pragma unroll
                for (int q = 0; q < 4; ++q)
                    gload16(B1g + (size_t)(q * 16) * K + k0 + 32,
                            (ushort_t*)&Bs[nxt][(w * 64 + q * 16) * 32]);
            }
            bf16x8 af[2], bfr[4];
            #pragma unroll
            for (int i = 0; i < 2; ++i)
                af[i] = *(const bf16x8*)&As[cur][(i * 16 + lrow) * 32 + rs];
            #pragma unroll
            for (int j = 0; j < 4; ++j)
                bfr[j] = *(const bf16x8*)&Bs[cur][(wn + j * 16 + lrow) * 32 + rs];
            #pragma unroll
            for (int i = 0; i < 2; ++i)
                #pragma unroll
                for (int j = 0; j < 4; ++j)
                    hh[i][j] = __builtin_amdgcn_mfma_f32_16x16x32_bf16(af[i], bfr[j], hh[i][j], 0, 0, 0);
        }

        // hidden chunk -> LDS (bias + relu, bf16)
        #pragma unroll
        for (int j = 0; j < 4; ++j) {
            int col = wn + j * 16 + lrow;
            float b1v = bias1[c * 256 + col];
            #pragma unroll
            for (int i = 0; i < 2; ++i)
                #pragma unroll
                for (int rg = 0; rg < 4; ++rg) {
                    int rl = i * 16 + quad * 4 + rg;
                    Hs[rl * 264 + col] = f2bf(fmaxf(hh[i][j][rg] + b1v, 0.f));
                }
        }
        __syncthreads();

        // GEMM2: acc += Hs[32x256] @ W2t[:, c*256+..]^T  (W2t: [256][1024])
        const ushort_t* B2g = W2t + (size_t)(w * 64 + srow) * 1024 + c * 256 + sw;
        #pragma unroll
        for (int q = 0; q < 4; ++q)
            gload16(B2g + (size_t)(q * 16) * 1024,
                    (ushort_t*)&Bs[0][(w * 64 + q * 16) * 32]);

        #pragma unroll
        for (int k0 = 0; k0 < 256; k0 += 32) {
            const int cur = (k0 >> 5) & 1;
            __syncthreads();
            if (k0 + 32 < 256) {
                const int nxt = cur ^ 1;
                #pragma unroll
                for (int q = 0; q < 4; ++q)
                    gload16(B2g + (size_t)(q * 16) * 1024 + k0 + 32,
                            (ushort_t*)&Bs[nxt][(w * 64 + q * 16) * 32]);
            }
            bf16x8 af[2], bfr[4];
            #pragma unroll
            for (int i = 0; i < 2; ++i)
                af[i] = *(const bf16x8*)&Hs[(i * 16 + lrow) * 264 + k0 + quad * 8];
            #pragma unroll
            for (int j = 0; j < 4; ++j)
                bfr[j] = *(const bf16x8*)&Bs[cur][(wn + j * 16 + lrow) * 32 + rs];
            #pragma unroll
            for (int i = 0; i < 2; ++i)
                #pragma unroll
                for (int j = 0; j < 4; ++j)
                    acc[i][j] = __builtin_amdgcn_mfma_f32_16x16x32_bf16(af[i], bfr[j], acc[i][j], 0, 0, 0);
        }
    }

    // ---- fused epilogue: v = x + (y + bias2); LN2; write x, xb, qb ----
    float gj[4], bj[4], bi[4];
    #pragma unroll
    for (int j = 0; j < 4; ++j) {
        int col = wn + j * 16 + lrow;
        gj[j] = lng[col];
        bj[j] = lnb[col];
        bi[j] = bias2[col];
    }

    #pragma unroll
    for (int i = 0; i < 2; ++i)
        #pragma unroll
        for (int rg = 0; rg < 4; ++rg) {
            int row = row0 + i * 16 + quad * 4 + rg;
            #pragma unroll
            for (int j = 0; j < 4; ++j) {
                int col = wn + j * 16 + lrow;
                float xres = (row < M) ? x[(size_t)row * 256 + col] : 0.f;
                acc[i][j][rg] += bi[j] + xres;
            }
            float p1 = acc[i][0][rg] + acc[i][1][rg] + acc[i][2][rg] + acc[i][3][rg];
            float p2 = acc[i][0][rg] * acc[i][0][rg] + acc[i][1][rg] * acc[i][1][rg]
                     + acc[i][2][rg] * acc[i][2][rg] + acc[i][3][rg] * acc[i][3][rg];
            p1 += __shfl_xor(p1, 1); p2 += __shfl_xor(p2, 1);
            p1 += __shfl_xor(p1, 2); p2 += __shfl_xor(p2, 2);
            p1 += __shfl_xor(p1, 4); p2 += __shfl_xor(p2, 4);
            p1 += __shfl_xor(p1, 8); p2 += __shfl_xor(p2, 8);
            if (lrow == 0) {
                int rl = i * 16 + quad * 4 + rg;
                red1[rl * 5 + w] = p1;
                red2[rl * 5 + w] = p2;
            }
        }
    __syncthreads();

    #pragma unroll
    for (int i = 0; i < 2; ++i)
        #pragma unroll
        for (int rg = 0; rg < 4; ++rg) {
            int rl = i * 16 + quad * 4 + rg;
            float S1 = red1[rl * 5 + 0] + red1[rl * 5 + 1] + red1[rl * 5 + 2] + red1[rl * 5 + 3];
            float S2 = red2[rl * 5 + 0] + red2[rl * 5 + 1] + red2[rl * 5 + 2] + red2[rl * 5 + 3];
            float mean = S1 * (1.f / 256);
            float rstd = rsqrtf(S2 * (1.f / 256) - mean * mean + 1e-5f);
            int row = row0 + rl;
            if (row < M) {
                #pragma unroll
                for (int j = 0; j < 4; ++j) {
                    int col = wn + j * 16 + lrow;
                    float out = (acc[i][j][rg] - mean) * rstd * gj[j] + bj[j];
                    size_t o = (size_t)row * 256 + col;
                    x[o]  = out;
                    xb[o] = f2bf(out);
                    qb[o] = f2bf(out + bf2f(posb[o]));
                }
            }
        }
}

// ---------------------------------------------------------------------------
// Fused deformable sampling, v7: XCD-pinned heads + 16B-lane gathers +
// relaxed VGPR cap for deep load pipelining.
// ---------------------------------------------------------------------------
__global__ __launch_bounds__(256, 4)
void sample_kernel(const ushort_t* __restrict__ valueb,
                   const ushort_t* __restrict__ offh,   // [NH][M][48]
                   const ushort_t* __restrict__ attnh,  // [NH][M][16]
                   ushort_t* __restrict__ sampb)
{
    __shared__ float wrec[16 * 168];
    __shared__ int   idxA[16 * 40];

    const int LD_[4]  = {4, 2, 1, 1};
    const int LH_[4]  = {48, 24, 12, 6};
    const int LW_[4]  = {48, 24, 12, 6};
    const int LS0_[4] = {0, 9216, 10368, 10512};

    int t   = threadIdx.x;
    int gl  = t >> 4;                   // local group 0..15
    int sub = t & 15;
    int h   = blockIdx.x;
    int r   = blockIdx.y * 16 + gl;
    bool valid = (r < M_ROWS);
    if (!valid) r = M_ROWS - 1;
    int b   = (r >= S_TOT) ? 1 : 0;
    int s   = r - b * S_TOT;

    float rx, ry, rz;
    {
        int j;
        if (s < 9216)       { j = s;         int qx = j % 48; int q2 = j / 48; int qy = q2 % 48; int qz = q2 / 48;
                              rx = (qx + 0.5f) * (1.f/48); ry = (qy + 0.5f) * (1.f/48); rz = (qz + 0.5f) * (1.f/4); }
        else if (s < 10368) { j = s - 9216;  int qx = j % 24; int q2 = j / 24; int qy = q2 % 24; int qz = q2 / 24;
                              rx = (qx + 0.5f) * (1.f/24); ry = (qy + 0.5f) * (1.f/24); rz = (qz + 0.5f) * (1.f/2); }
        else if (s < 10512) { j = s - 10368; int qx = j % 12; int qy = j / 12;
                              rx = (qx + 0.5f) * (1.f/12); ry = (qy + 0.5f) * (1.f/12); rz = 0.5f; }
        else                { j = s - 10512; int qx = j % 6;  int qy = j / 6;
                              rx = (qx + 0.5f) * (1.f/6);  ry = (qy + 0.5f) * (1.f/6);  rz = 0.5f; }
    }

    // ---- phase 1: one point per lane ----
    {
        int p = sub;
        float lg = bf2f(attnh[((size_t)h * M_ROWS + r) * 16 + p]);
        float mx = lg;
        mx = fmaxf(mx, __shfl_xor(mx, 1));
        mx = fmaxf(mx, __shfl_xor(mx, 2));
        mx = fmaxf(mx, __shfl_xor(mx, 4));
        mx = fmaxf(mx, __shfl_xor(mx, 8));
        float e = __expf(lg - mx);
        float sm = e;
        sm += __shfl_xor(sm, 1);
        sm += __shfl_xor(sm, 2);
        sm += __shfl_xor(sm, 4);
        sm += __shfl_xor(sm, 8);
        float aw = e / sm;

        int lvl = p >> 2;
        const int Dl = LD_[lvl], Hl = LH_[lvl], Wl = LW_[lvl];
        size_t base3 = ((size_t)h * M_ROWS + r) * 48 + p * 3;
        float cx = rx * Wl + bf2f(offh[base3 + 0]) - 0.5f;
        float cy = ry * Hl + bf2f(offh[base3 + 1]) - 0.5f;
        float cz = rz * Dl + bf2f(offh[base3 + 2]) - 0.5f;
        float xf = floorf(cx), yf = floorf(cy), zf = floorf(cz);
        float fx = cx - xf, fy = cy - yf, fz = cz - zf;
        int x0 = (int)xf, y0 = (int)yf, z0 = (int)zf;
        float wx0 = ((unsigned)x0       < (unsigned)Wl) ? 1.f - fx : 0.f;
        float wx1 = ((unsigned)(x0 + 1) < (unsigned)Wl) ? fx       : 0.f;
        float wy0 = ((unsigned)y0       < (unsigned)Hl) ? 1.f - fy : 0.f;
        float wy1 = ((unsigned)(y0 + 1) < (unsigned)Hl) ? fy       : 0.f;
        float wz0 = ((unsigned)z0       < (unsigned)Dl) ? (1.f - fz) * aw : 0.f;
        float wz1 = ((unsigned)(z0 + 1) < (unsigned)Dl) ? fz * aw       : 0.f;
        int xc = min(max(x0, -1), Wl - 1);
        int yc = min(max(y0, -1), Hl - 1);
        int zc = min(max(z0, -1), Dl - 1);
        int idx = LS0_[lvl] + (zc * Hl + yc) * Wl + xc;

        float* wp = &wrec[gl * 168 + p * 8];
        *(f32x4*)wp       = (f32x4){wz0 * wy0 * wx0, wz0 * wy0 * wx1,
                                    wz0 * wy1 * wx0, wz0 * wy1 * wx1};
        *(f32x4*)(wp + 4) = (f32x4){wz1 * wy0 * wx0, wz1 * wy0 * wx1,
                                    wz1 * wy1 * wx0, wz1 * wy1 * wx1};
        idxA[gl * 40 + p] = idx;
    }
    __syncthreads();

    // ---- phase 2: corner cr = (dy,dx), channel octet q ----
    int q  = sub & 3;
    int cr = sub >> 2;
    int dy = cr >> 1, dx = cr & 1;
    const ushort_t* vb = valueb + ((size_t)(b * NH_DIM + h) * S_TOT) * HD_DIM + q * 8;
    f32x4 accA = (f32x4){0.f, 0.f, 0.f, 0.f};
    f32x4 accB = (f32x4){0.f, 0.f, 0.f, 0.f};

    #pragma unroll
    for (int p = 0; p < 16; ++p) {
        const int lvl = p >> 2;
        const int Wl = LW_[lvl];
        const int HW = LH_[lvl] * LW_[lvl];
        float w0 = wrec[gl * 168 + p * 8 + cr];
        float w1 = wrec[gl * 168 + p * 8 + 4 + cr];
        int idx = idxA[gl * 40 + p] + dy * Wl + dx;
        const ushort_t* cb = vb + (long long)idx * HD_DIM;
        uint4 u0 = *(const uint4*)cb;
        uint4 u1 = *(const uint4*)(cb + HW * HD_DIM);
        accA += w0 * up2(u0.x, u0.y);
        accB += w0 * up2(u0.z, u0.w);
        accA += w1 * up2(u1.x, u1.y);
        accB += w1 * up2(u1.z, u1.w);
    }

    accA.x += __shfl_xor(accA.x, 4); accA.y += __shfl_xor(accA.y, 4);
    accA.z += __shfl_xor(accA.z, 4); accA.w += __shfl_xor(accA.w, 4);
    accB.x += __shfl_xor(accB.x, 4); accB.y += __shfl_xor(accB.y, 4);
    accB.z += __shfl_xor(accB.z, 4); accB.w += __shfl_xor(accB.w, 4);
    accA.x += __shfl_xor(accA.x, 8); accA.y += __shfl_xor(accA.y, 8);
    accA.z += __shfl_xor(accA.z, 8); accA.w += __shfl_xor(accA.w, 8);
    accB.x += __shfl_xor(accB.x, 8); accB.y += __shfl_xor(accB.y, 8);
    accB.z += __shfl_xor(accB.z, 8); accB.w += __shfl_xor(accB.w, 8);

    if (cr == 0 && valid) {
        ushort4 o1, o2;
        o1.x = f2bf(accA.x); o1.y = f2bf(accA.y); o1.z = f2bf(accA.z); o1.w = f2bf(accA.w);
        o2.x = f2bf(accB.x); o2.y = f2bf(accB.y); o2.z = f2bf(accB.z); o2.w = f2bf(accB.w);
        ushort_t* op = sampb + (size_t)r * E_DIM + h * HD_DIM + q * 8;
        *(ushort4*)op       = o1;
        *(ushort4*)(op + 4) = o2;
    }
}

// ---------------------------------------------------------------------------
extern "C" void kernel_launch(void* const* d_in, const int* in_sizes, int n_in,
                              void* d_out, int out_size, void* d_ws, size_t ws_size,
                              hipStream_t stream)
{
    const float* f0     = (const float*)d_in[0];
    const float* p0     = (const float*)d_in[1];
    const float* f1     = (const float*)d_in[2];
    const float* p1     = (const float*)d_in[3];
    const float* f2     = (const float*)d_in[4];
    const float* p2     = (const float*)d_in[5];
    const float* f3     = (const float*)d_in[6];
    const float* p3     = (const float*)d_in[7];
    const float* lemb   = (const float*)d_in[8];
    const float* W_off  = (const float*)d_in[9];
    const float* b_off  = (const float*)d_in[10];
    const float* W_attn = (const float*)d_in[11];
    const float* b_attn = (const float*)d_in[12];
    const float* W_val  = (const float*)d_in[13];
    const float* b_val  = (const float*)d_in[14];
    const float* W_out  = (const float*)d_in[15];
    const float* b_out  = (const float*)d_in[16];
    const float* ln1_g  = (const float*)d_in[17];
    const float* ln1_b  = (const float*)d_in[18];
    const float* W_ff1  = (const float*)d_in[19];
    const float* b_ff1  = (const float*)d_in[20];
    const float* W_ff2  = (const float*)d_in[21];
    const float* b_ff2  = (const float*)d_in[22];
    const float* ln2_g  = (const float*)d_in[23];
    const float* ln2_b  = (const float*)d_in[24];

    float* x = (float*)d_out;
    char*  w = (char*)d_ws;

    // ws layout (bytes)
    ushort_t* posb   = (ushort_t*)(w + 0);                   // 10,813,440
    // value region: 256KB front guard | (B,NH,S,HD) bf16 | 128KB back guard
    ushort_t* valueb = (ushort_t*)(w + 21626880 + 262144);
    char*     region =            (w + 34525184);            // 43,253,760
    ushort_t* offh   = (ushort_t*)(region);                  // [NH][M][48] 16,220,160
    ushort_t* attnh  = (ushort_t*)(region + 16220160);       // [NH][M][16]  5,406,720
    ushort_t* sampb  = (ushort_t*)(region + 21626880);       // 10,813,440
    ushort_t* xb     = (ushort_t*)(w + 77778944);            // 10,813,440
    ushort_t* qb     = (ushort_t*)(w + 88592384);            // 10,813,440
    ushort_t* wb     = (ushort_t*)(w + 99405824);            //  9,437,184

    // Combined attention weight: per layer 768 rows x 256 K
    ushort_t* Wc_t = wb;              // [6][768][256]
    ushort_t* Wp_t = wb + 1179648;    // [6][256][256]
    ushort_t* W1_t = wb + 1572864;    // [6][1024][256]
    ushort_t* W2_t = wb + 3145728;    // [6][256][1024]

    dim3 blk(256);

    transpose_cvt_kernel<<<dim3(8, 8, 6),  blk, 0, stream>>>(W_val,  Wc_t, 256, 256,  196608, 0);
    transpose_cvt_kernel<<<dim3(12, 8, 6), blk, 0, stream>>>(W_off,  Wc_t, 256, 384,  196608, 256);
    transpose_cvt_kernel<<<dim3(4, 8, 6),  blk, 0, stream>>>(W_attn, Wc_t, 256, 128,  196608, 640);
    transpose_cvt_kernel<<<dim3(8, 8, 6),  blk, 0, stream>>>(W_out,  Wp_t, 256, 256,   65536, 0);
    transpose_cvt_kernel<<<dim3(32, 8, 6), blk, 0, stream>>>(W_ff1,  W1_t, 256, 1024, 262144, 0);
    transpose_cvt_kernel<<<dim3(8, 32, 6), blk, 0, stream>>>(W_ff2,  W2_t, 1024, 256, 262144, 0);

    // 331 j-tiles (288+36+5+2), 8 e-tiles, 2 batches
    assemble_kernel<<<dim3(331, 8, 2), blk, 0, stream>>>(
        f0, p0, f1, p1, f2, p2, f3, p3, lemb, x, posb, xb, qb);

    const int MT = M_PAD / 64;               // 330 (part1 grid.y)
    const int LT = M_PAD / 32;               // 660 (gemm_ln / ffn grids)
    const int SB = (M_ROWS + 15) / 16;       // 1319
    for (int l = 0; l < NLAYERS; ++l) {
        gemm_part1<<<dim3(3, MT), blk, 0, stream>>>(
            xb, qb, Wc_t + l * 196608,
            b_val + l * 256, b_off + l * 384, b_attn + l * 128,
            valueb, offh, attnh, M_ROWS);
        sample_kernel<<<dim3(NH_DIM, SB), blk, 0, stream>>>(valueb, offh, attnh, sampb);
        gemm_ln<<<LT, blk, 0, stream>>>(
            sampb, Wp_t + l * 65536, b_out + l * 256,
            x, xb, ln1_g + l * 256, ln1_b + l * 256, M_ROWS);
        ffn_kernel<<<LT, blk, 0, stream>>>(
            xb, W1_t + l * 262144, W2_t + l * 262144,
            b_ff1 + l * 1024, b_ff2 + l * 256,
            x, xb, qb, posb,
            ln2_g + l * 256, ln2_b + l * 256, M_ROWS);
    }
}

// Round 14
// 1079.036 us; speedup vs baseline: 1.2016x; 1.0296x over previous
//
#include <hip/hip_runtime.h>

#define S_TOT   10548
#define M_ROWS  21096
#define M_PAD   21120          // 330*64 = 660*32
#define E_DIM   256
#define NH_DIM  8
#define HD_DIM  32
#define DF_DIM  1024
#define NLAYERS 6
#define GUARD_USH 131072       // 256KB front guard, in ushorts

typedef unsigned short ushort_t;
typedef __attribute__((ext_vector_type(8))) short bf16x8;
typedef __attribute__((ext_vector_type(4))) float f32x4;

__device__ inline ushort_t f2bf(float f) {
    unsigned u = __float_as_uint(f);
    u += 0x7FFF + ((u >> 16) & 1);          // RNE
    return (ushort_t)(u >> 16);
}
__device__ inline float bf2f(ushort_t h) {
    return __uint_as_float(((unsigned)h) << 16);
}
__device__ inline f32x4 up2(unsigned a, unsigned b) {
    f32x4 v;
    v.x = __uint_as_float(a << 16);
    v.y = __uint_as_float(a & 0xffff0000u);
    v.z = __uint_as_float(b << 16);
    v.w = __uint_as_float(b & 0xffff0000u);
    return v;
}
// async global->LDS, 16B per lane; LDS dest wave-uniform, lane scatters at
// dest + lane*16.
__device__ inline void gload16(const ushort_t* g, ushort_t* l) {
    __builtin_amdgcn_global_load_lds(
        (const __attribute__((address_space(1))) void*)g,
        (__attribute__((address_space(3))) void*)l, 16, 0, 0);
}

// ---------------------------------------------------------------------------
// Input assembly v2: LDS-transpose tiles, both sides coalesced.
// grid = (331 j-tiles, 8 e-tiles, 2 batches).
// ---------------------------------------------------------------------------
__global__ __launch_bounds__(256)
void assemble_kernel(const float* __restrict__ f0, const float* __restrict__ p0,
                     const float* __restrict__ f1, const float* __restrict__ p1,
                     const float* __restrict__ f2, const float* __restrict__ p2,
                     const float* __restrict__ f3, const float* __restrict__ p3,
                     const float* __restrict__ lemb,
                     float* __restrict__ x, ushort_t* __restrict__ posb,
                     ushort_t* __restrict__ xb, ushort_t* __restrict__ qb)
{
    __shared__ float tf[32][33];
    __shared__ float tp[32][33];

    int tb = blockIdx.x;
    int e0 = blockIdx.y * 32;
    int b  = blockIdx.z;
    int lvl, j0, n, s0; const float* f; const float* p;
    if (tb < 288)      { lvl = 0; j0 = tb * 32;         n = 9216; s0 = 0;     f = f0; p = p0; }
    else if (tb < 324) { lvl = 1; j0 = (tb - 288) * 32; n = 1152; s0 = 9216;  f = f1; p = p1; }
    else if (tb < 329) { lvl = 2; j0 = (tb - 324) * 32; n = 144;  s0 = 10368; f = f2; p = p2; }
    else               { lvl = 3; j0 = (tb - 329) * 32; n = 36;   s0 = 10512; f = f3; p = p3; }

    int tx = threadIdx.x & 31, ty = threadIdx.x >> 5;
    bool jv = (j0 + tx) < n;
    size_t base = (size_t)(b * E_DIM + e0) * n + j0 + tx;
    #pragma unroll
    for (int i = 0; i < 4; ++i) {
        int e = ty + i * 8;
        float fv = 0.f, pv = 0.f;
        if (jv) {
            fv = f[base + (size_t)e * n];
            pv = p[base + (size_t)e * n];
        }
        tf[e][tx] = fv;
        tp[e][tx] = pv;
    }
    __syncthreads();

    float lv = lemb[lvl * E_DIM + e0 + tx];
    #pragma unroll
    for (int i = 0; i < 4; ++i) {
        int jl = ty + i * 8;
        if (j0 + jl < n) {
            int r = b * S_TOT + s0 + j0 + jl;
            float xv = tf[tx][jl];
            float pv = tp[tx][jl] + lv;
            size_t o = (size_t)r * E_DIM + e0 + tx;
            x[o]    = xv;
            posb[o] = f2bf(pv);
            xb[o]   = f2bf(xv);
            qb[o]   = f2bf(xv + pv);
        }
    }
}

// ---------------------------------------------------------------------------
// Weight convert+transpose: src f32 [L,K,N] -> dst bf16 [L(stride), rowOff+N, K]
// ---------------------------------------------------------------------------
__global__ __launch_bounds__(256)
void transpose_cvt_kernel(const float* __restrict__ src, ushort_t* __restrict__ dst,
                          int K, int N, int dstLayerStride, int dstRowOff)
{
    __shared__ float tile[32][33];
    int l  = blockIdx.z;
    int n0 = blockIdx.x * 32, k0 = blockIdx.y * 32;
    int tx = threadIdx.x & 31, ty = threadIdx.x >> 5;
    const float* s = src + (size_t)l * K * N;
    ushort_t* d    = dst + (size_t)l * dstLayerStride + (size_t)dstRowOff * K;
    #pragma unroll
    for (int i = 0; i < 32; i += 8)
        tile[ty + i][tx] = s[(size_t)(k0 + ty + i) * N + n0 + tx];
    __syncthreads();
    #pragma unroll
    for (int i = 0; i < 32; i += 8)
        d[(size_t)(n0 + ty + i) * K + k0 + tx] = f2bf(tile[tx][ty + i]);
}

// ---------------------------------------------------------------------------
// 64x256-tile bf16 MFMA GEMM (part1), double-buffered single-sync K-loop.
// grid.x=sup: 0=value (A=xb, permute store), 1=off[0:256),
// 2=off[256:384)+attn (A=qb); off/attn stored HEAD-MAJOR.
// ---------------------------------------------------------------------------
__global__ __launch_bounds__(256, 4)
void gemm_part1(const ushort_t* __restrict__ A0, const ushort_t* __restrict__ A1,
                const ushort_t* __restrict__ BtBase,
                const float* __restrict__ b1, const float* __restrict__ b2,
                const float* __restrict__ b3,
                ushort_t* __restrict__ O1, ushort_t* __restrict__ O2,
                ushort_t* __restrict__ O3, int M)
{
    __shared__ short As[2][64 * 32];
    __shared__ short Bs[2][256 * 32];
    const int K = 256;
    int t    = threadIdx.x;
    int sup  = blockIdx.x;
    int row0 = blockIdx.y * 64;
    int lane = t & 63;
    int w    = t >> 6;
    int wn   = w * 64;
    const int quad = lane >> 4, lrow = lane & 15;

    const ushort_t* A  = (sup != 0) ? A1 : A0;
    const ushort_t* Bt = BtBase + (size_t)sup * 256 * K;

    f32x4 acc[4][4];
    #pragma unroll
    for (int i = 0; i < 4; ++i)
        #pragma unroll
        for (int j = 0; j < 4; ++j)
            acc[i][j] = (f32x4){0.f, 0.f, 0.f, 0.f};

    int srow = lane >> 2;
    const int sw = (((lane & 3) ^ ((lane >> 3) & 3)) * 8);     // swizzled k-seg
    const int rs = ((quad ^ ((lrow >> 1) & 3)) * 8);           // fragment slot
    const ushort_t* Ag = A + (size_t)(row0 + w * 16 + srow) * K + sw;
    const ushort_t* Bg = Bt + (size_t)(w * 64 + srow) * K + sw;

    // prologue: stage k0=0 into buffer 0
    gload16(Ag, (ushort_t*)&As[0][(w * 16) * 32]);
    #pragma unroll
    for (int q = 0; q < 4; ++q)
        gload16(Bg + (size_t)(q * 16) * K,
                (ushort_t*)&Bs[0][(w * 64 + q * 16) * 32]);

    #pragma unroll
    for (int k0 = 0; k0 < K; k0 += 32) {
        const int cur = (k0 >> 5) & 1;
        __syncthreads();                      // stage(k) landed; buf cur^1 free
        if (k0 + 32 < K) {
            const int nxt = cur ^ 1;
            gload16(Ag + k0 + 32, (ushort_t*)&As[nxt][(w * 16) * 32]);
            #pragma unroll
            for (int q = 0; q < 4; ++q)
                gload16(Bg + (size_t)(q * 16) * K + k0 + 32,
                        (ushort_t*)&Bs[nxt][(w * 64 + q * 16) * 32]);
        }
        bf16x8 af[4], bfr[4];
        #pragma unroll
        for (int i = 0; i < 4; ++i)
            af[i] = *(const bf16x8*)&As[cur][(i * 16 + lrow) * 32 + rs];
        #pragma unroll
        for (int j = 0; j < 4; ++j)
            bfr[j] = *(const bf16x8*)&Bs[cur][(wn + j * 16 + lrow) * 32 + rs];
        #pragma unroll
        for (int i = 0; i < 4; ++i)
            #pragma unroll
            for (int j = 0; j < 4; ++j)
                acc[i][j] = __builtin_amdgcn_mfma_f32_16x16x32_bf16(af[i], bfr[j], acc[i][j], 0, 0, 0);
    }

    #pragma unroll
    for (int j = 0; j < 4; ++j) {
        int col = wn + j * 16 + lrow;     // 0..255 local
        float bia = (sup == 0) ? b1[col]
                  : (sup == 1) ? b2[col]
                  : (col < 128) ? b2[256 + col] : b3[col - 128];
        #pragma unroll
        for (int i = 0; i < 4; ++i)
            #pragma unroll
            for (int rg = 0; rg < 4; ++rg) {
                int row = row0 + i * 16 + quad * 4 + rg;
                if (row < M) {
                    float v = acc[i][j][rg] + bia;
                    if (sup == 0) {
                        int b = (row >= S_TOT) ? 1 : 0;
                        int s = row - b * S_TOT;
                        O1[(((size_t)(b * NH_DIM + (col >> 5))) * S_TOT + s) * HD_DIM + (col & 31)] = f2bf(v);
                    } else if (sup == 2 && col >= 128) {
                        int acol = col - 128;
                        O3[((size_t)(acol >> 4) * M_ROWS + row) * 16 + (acol & 15)] = f2bf(v);
                    } else {
                        int ocol = (sup == 1) ? col : 256 + col;
                        int hh = (ocol * 1366) >> 16;            // /48
                        O2[((size_t)hh * M_ROWS + row) * 48 + (ocol - hh * 48)] = f2bf(v);
                    }
                }
            }
    }
}

// ---------------------------------------------------------------------------
// 32x256-tile bf16 MFMA GEMM + FUSED residual + LayerNorm epilogue (out-proj).
// Double-buffered single-sync K-loop; red scratch aliased onto As[0].
// LDS 36KB -> 4 blocks/CU.
// ---------------------------------------------------------------------------
__global__ __launch_bounds__(256, 4)
void gemm_ln(const ushort_t* __restrict__ A, const ushort_t* __restrict__ Bt,
             const float* __restrict__ bias,
             float* __restrict__ x, ushort_t* __restrict__ xb,
             const float* __restrict__ lng, const float* __restrict__ lnb,
             int M)
{
    __shared__ short As[2][32 * 32];
    __shared__ short Bs[2][256 * 32];
    float* red1 = (float*)&As[0][0];          // 160 floats
    float* red2 = red1 + 32 * 5;              // 160 floats (1280B <= 2048B)
    const int K = 256;
    int t    = threadIdx.x;
    int row0 = blockIdx.x * 32;
    int lane = t & 63;
    int w    = t >> 6;
    int wn   = w * 64;
    const int quad = lane >> 4, lrow = lane & 15;

    f32x4 acc[2][4];
    #pragma unroll
    for (int i = 0; i < 2; ++i)
        #pragma unroll
        for (int j = 0; j < 4; ++j)
            acc[i][j] = (f32x4){0.f, 0.f, 0.f, 0.f};

    int srow = lane >> 2;
    const int sw = (((lane & 3) ^ ((lane >> 3) & 3)) * 8);
    const int rs = ((quad ^ ((lrow >> 1) & 3)) * 8);
    const ushort_t* Ag = A + (size_t)(row0 + w * 16 + srow) * K + sw;   // w<2
    const ushort_t* Bg = Bt + (size_t)(w * 64 + srow) * K + sw;

    if (w < 2) gload16(Ag, (ushort_t*)&As[0][(w * 16) * 32]);
    #pragma unroll
    for (int q = 0; q < 4; ++q)
        gload16(Bg + (size_t)(q * 16) * K,
                (ushort_t*)&Bs[0][(w * 64 + q * 16) * 32]);

    #pragma unroll
    for (int k0 = 0; k0 < K; k0 += 32) {
        const int cur = (k0 >> 5) & 1;
        __syncthreads();
        if (k0 + 32 < K) {
            const int nxt = cur ^ 1;
            if (w < 2) gload16(Ag + k0 + 32, (ushort_t*)&As[nxt][(w * 16) * 32]);
            #pragma unroll
            for (int q = 0; q < 4; ++q)
                gload16(Bg + (size_t)(q * 16) * K + k0 + 32,
                        (ushort_t*)&Bs[nxt][(w * 64 + q * 16) * 32]);
        }
        bf16x8 af[2], bfr[4];
        #pragma unroll
        for (int i = 0; i < 2; ++i)
            af[i] = *(const bf16x8*)&As[cur][(i * 16 + lrow) * 32 + rs];
        #pragma unroll
        for (int j = 0; j < 4; ++j)
            bfr[j] = *(const bf16x8*)&Bs[cur][(wn + j * 16 + lrow) * 32 + rs];
        #pragma unroll
        for (int i = 0; i < 2; ++i)
            #pragma unroll
            for (int j = 0; j < 4; ++j)
                acc[i][j] = __builtin_amdgcn_mfma_f32_16x16x32_bf16(af[i], bfr[j], acc[i][j], 0, 0, 0);
    }

    // ---- fused epilogue: v = x + (y + bias); LayerNorm per row ----
    float gj[4], bj[4], bi[4];
    #pragma unroll
    for (int j = 0; j < 4; ++j) {
        int col = wn + j * 16 + lrow;
        gj[j] = lng[col];
        bj[j] = lnb[col];
        bi[j] = bias[col];
    }

    #pragma unroll
    for (int i = 0; i < 2; ++i)
        #pragma unroll
        for (int rg = 0; rg < 4; ++rg) {
            int row = row0 + i * 16 + quad * 4 + rg;
            #pragma unroll
            for (int j = 0; j < 4; ++j) {
                int col = wn + j * 16 + lrow;
                float xres = (row < M) ? x[(size_t)row * 256 + col] : 0.f;
                acc[i][j][rg] += bi[j] + xres;
            }
            float p1 = acc[i][0][rg] + acc[i][1][rg] + acc[i][2][rg] + acc[i][3][rg];
            float p2 = acc[i][0][rg] * acc[i][0][rg] + acc[i][1][rg] * acc[i][1][rg]
                     + acc[i][2][rg] * acc[i][2][rg] + acc[i][3][rg] * acc[i][3][rg];
            p1 += __shfl_xor(p1, 1); p2 += __shfl_xor(p2, 1);
            p1 += __shfl_xor(p1, 2); p2 += __shfl_xor(p2, 2);
            p1 += __shfl_xor(p1, 4); p2 += __shfl_xor(p2, 4);
            p1 += __shfl_xor(p1, 8); p2 += __shfl_xor(p2, 8);
            if (lrow == 0) {
                int rl = i * 16 + quad * 4 + rg;
                red1[rl * 5 + w] = p1;
                red2[rl * 5 + w] = p2;
            }
        }
    __syncthreads();

    #pragma unroll
    for (int i = 0; i < 2; ++i)
        #pragma unroll
        for (int rg = 0; rg < 4; ++rg) {
            int rl = i * 16 + quad * 4 + rg;
            float S1 = red1[rl * 5 + 0] + red1[rl * 5 + 1] + red1[rl * 5 + 2] + red1[rl * 5 + 3];
            float S2 = red2[rl * 5 + 0] + red2[rl * 5 + 1] + red2[rl * 5 + 2] + red2[rl * 5 + 3];
            float mean = S1 * (1.f / 256);
            float rstd = rsqrtf(S2 * (1.f / 256) - mean * mean + 1e-5f);
            int row = row0 + rl;
            if (row < M) {
                #pragma unroll
                for (int j = 0; j < 4; ++j) {
                    int col = wn + j * 16 + lrow;
                    float out = (acc[i][j][rg] - mean) * rstd * gj[j] + bj[j];
                    size_t o = (size_t)row * 256 + col;
                    x[o]  = out;
                    xb[o] = f2bf(out);
                }
            }
        }
}

// ---------------------------------------------------------------------------
// FUSED FFN (exact R5 measured-best): x = LN2(x + relu(xb@W1+b1)@W2 + b2);
// also xb, qb outputs. 32-row block; hidden in 4 chunks of 256, kept in LDS.
// Double-buffered single-sync K-loops; red aliased onto As[0].
// LDS 52.5KB. Measured 67 us/dispatch, VGPR 76.
// ---------------------------------------------------------------------------
__global__ __launch_bounds__(256, 2)
void ffn_kernel(const ushort_t* __restrict__ Axb, const ushort_t* __restrict__ W1t,
                const ushort_t* __restrict__ W2t,
                const float* __restrict__ bias1, const float* __restrict__ bias2,
                float* __restrict__ x, ushort_t* __restrict__ xb,
                ushort_t* __restrict__ qb, const ushort_t* __restrict__ posb,
                const float* __restrict__ lng, const float* __restrict__ lnb,
                int M)
{
    __shared__ short As[2][32 * 32];
    __shared__ short Bs[2][256 * 32];
    __shared__ short Hs[32 * 264];
    float* red1 = (float*)&As[0][0];          // aliased; safe (see gemm_ln)
    float* red2 = red1 + 32 * 5;
    const int K = 256;
    int t    = threadIdx.x;
    int row0 = blockIdx.x * 32;
    int lane = t & 63;
    int w    = t >> 6;
    int wn   = w * 64;
    const int quad = lane >> 4, lrow = lane & 15;
    int srow = lane >> 2;
    const int sw = (((lane & 3) ^ ((lane >> 3) & 3)) * 8);
    const int rs = ((quad ^ ((lrow >> 1) & 3)) * 8);

    f32x4 acc[2][4];
    #pragma unroll
    for (int i = 0; i < 2; ++i)
        #pragma unroll
        for (int j = 0; j < 4; ++j)
            acc[i][j] = (f32x4){0.f, 0.f, 0.f, 0.f};

    const ushort_t* Ag = Axb + (size_t)(row0 + w * 16 + srow) * K + sw;  // w<2

    for (int c = 0; c < 4; ++c) {
        f32x4 hh[2][4];
        #pragma unroll
        for (int i = 0; i < 2; ++i)
            #pragma unroll
            for (int j = 0; j < 4; ++j)
                hh[i][j] = (f32x4){0.f, 0.f, 0.f, 0.f};

        // GEMM1: hh = xb[32xK] @ W1t[c*256+: 256 rows][K]^T
        const ushort_t* B1g = W1t + (size_t)(c * 256 + w * 64 + srow) * K + sw;

        __syncthreads();    // prev chunk's GEMM2 done reading Bs
        if (w < 2) gload16(Ag, (ushort_t*)&As[0][(w * 16) * 32]);
        #pragma unroll
        for (int q = 0; q < 4; ++q)
            gload16(B1g + (size_t)(q * 16) * K,
                    (ushort_t*)&Bs[0][(w * 64 + q * 16) * 32]);

        #pragma unroll
        for (int k0 = 0; k0 < K; k0 += 32) {
            const int cur = (k0 >> 5) & 1;
            __syncthreads();
            if (k0 + 32 < K) {
                const int nxt = cur ^ 1;
                if (w < 2) gload16(Ag + k0 + 32, (ushort_t*)&As[nxt][(w * 16) * 32]);
                #pragma unroll
                for (int q = 0; q < 4; ++q)
                    gload16(B1g + (size_t)(q * 16) * K + k0 + 32,
                            (ushort_t*)&Bs[nxt][(w * 64 + q * 16) * 32]);
            }
            bf16x8 af[2], bfr[4];
            #pragma unroll
            for (int i = 0; i < 2; ++i)
                af[i] = *(const bf16x8*)&As[cur][(i * 16 + lrow) * 32 + rs];
            #pragma unroll
            for (int j = 0; j < 4; ++j)
                bfr[j] = *(const bf16x8*)&Bs[cur][(wn + j * 16 + lrow) * 32 + rs];
            #pragma unroll
            for (int i = 0; i < 2; ++i)
                #pragma unroll
                for (int j = 0; j < 4; ++j)
                    hh[i][j] = __builtin_amdgcn_mfma_f32_16x16x32_bf16(af[i], bfr[j], hh[i][j], 0, 0, 0);
        }

        // hidden chunk -> LDS (bias + relu, bf16)
        #pragma unroll
        for (int j = 0; j < 4; ++j) {
            int col = wn + j * 16 + lrow;
            float b1v = bias1[c * 256 + col];
            #pragma unroll
            for (int i = 0; i < 2; ++i)
                #pragma unroll
                for (int rg = 0; rg < 4; ++rg) {
                    int rl = i * 16 + quad * 4 + rg;
                    Hs[rl * 264 + col] = f2bf(fmaxf(hh[i][j][rg] + b1v, 0.f));
                }
        }
        __syncthreads();

        // GEMM2: acc += Hs[32x256] @ W2t[:, c*256+..]^T  (W2t: [256][1024])
        const ushort_t* B2g = W2t + (size_t)(w * 64 + srow) * 1024 + c * 256 + sw;
        #pragma unroll
        for (int q = 0; q < 4; ++q)
            gload16(B2g + (size_t)(q * 16) * 1024,
                    (ushort_t*)&Bs[0][(w * 64 + q * 16) * 32]);

        #pragma unroll
        for (int k0 = 0; k0 < 256; k0 += 32) {
            const int cur = (k0 >> 5) & 1;
            __syncthreads();
            if (k0 + 32 < 256) {
                const int nxt = cur ^ 1;
                #pragma unroll
                for (int q = 0; q < 4; ++q)
                    gload16(B2g + (size_t)(q * 16) * 1024 + k0 + 32,
                            (ushort_t*)&Bs[nxt][(w * 64 + q * 16) * 32]);
            }
            bf16x8 af[2], bfr[4];
            #pragma unroll
            for (int i = 0; i < 2; ++i)
                af[i] = *(const bf16x8*)&Hs[(i * 16 + lrow) * 264 + k0 + quad * 8];
            #pragma unroll
            for (int j = 0; j < 4; ++j)
                bfr[j] = *(const bf16x8*)&Bs[cur][(wn + j * 16 + lrow) * 32 + rs];
            #pragma unroll
            for (int i = 0; i < 2; ++i)
                #pragma unroll
                for (int j = 0; j < 4; ++j)
                    acc[i][j] = __builtin_amdgcn_mfma_f32_16x16x32_bf16(af[i], bfr[j], acc[i][j], 0, 0, 0);
        }
    }

    // ---- fused epilogue: v = x + (y + bias2); LN2; write x, xb, qb ----
    float gj[4], bj[4], bi[4];
    #pragma unroll
    for (int j = 0; j < 4; ++j) {
        int col = wn + j * 16 + lrow;
        gj[j] = lng[col];
        bj[j] = lnb[col];
        bi[j] = bias2[col];
    }

    #pragma unroll
    for (int i = 0; i < 2; ++i)
        #pragma unroll
        for (int rg = 0; rg < 4; ++rg) {
            int row = row0 + i * 16 + quad * 4 + rg;
            #pragma unroll
            for (int j = 0; j < 4; ++j) {
                int col = wn + j * 16 + lrow;
                float xres = (row < M) ? x[(size_t)row * 256 + col] : 0.f;
                acc[i][j][rg] += bi[j] + xres;
            }
            float p1 = acc[i][0][rg] + acc[i][1][rg] + acc[i][2][rg] + acc[i][3][rg];
            float p2 = acc[i][0][rg] * acc[i][0][rg] + acc[i][1][rg] * acc[i][1][rg]
                     + acc[i][2][rg] * acc[i][2][rg] + acc[i][3][rg] * acc[i][3][rg];
            p1 += __shfl_xor(p1, 1); p2 += __shfl_xor(p2, 1);
            p1 += __shfl_xor(p1, 2); p2 += __shfl_xor(p2, 2);
            p1 += __shfl_xor(p1, 4); p2 += __shfl_xor(p2, 4);
            p1 += __shfl_xor(p1, 8); p2 += __shfl_xor(p2, 8);
            if (lrow == 0) {
                int rl = i * 16 + quad * 4 + rg;
                red1[rl * 5 + w] = p1;
                red2[rl * 5 + w] = p2;
            }
        }
    __syncthreads();

    #pragma unroll
    for (int i = 0; i < 2; ++i)
        #pragma unroll
        for (int rg = 0; rg < 4; ++rg) {
            int rl = i * 16 + quad * 4 + rg;
            float S1 = red1[rl * 5 + 0] + red1[rl * 5 + 1] + red1[rl * 5 + 2] + red1[rl * 5 + 3];
            float S2 = red2[rl * 5 + 0] + red2[rl * 5 + 1] + red2[rl * 5 + 2] + red2[rl * 5 + 3];
            float mean = S1 * (1.f / 256);
            float rstd = rsqrtf(S2 * (1.f / 256) - mean * mean + 1e-5f);
            int row = row0 + rl;
            if (row < M) {
                #pragma unroll
                for (int j = 0; j < 4; ++j) {
                    int col = wn + j * 16 + lrow;
                    float out = (acc[i][j][rg] - mean) * rstd * gj[j] + bj[j];
                    size_t o = (size_t)row * 256 + col;
                    x[o]  = out;
                    xb[o] = f2bf(out);
                    qb[o] = f2bf(out + bf2f(posb[o]));
                }
            }
        }
}

// ---------------------------------------------------------------------------
// Fused deformable sampling, v8: v7 + uniform-SGPR-base 32-bit addressing.
// base = valueb - GUARD_USH (guard start) keeps all u32 offsets positive;
// idxA stores pre-scaled, pre-biased element offsets.
// ---------------------------------------------------------------------------
__global__ __launch_bounds__(256, 4)
void sample_kernel(const ushort_t* __restrict__ valueb,
                   const ushort_t* __restrict__ offh,   // [NH][M][48]
                   const ushort_t* __restrict__ attnh,  // [NH][M][16]
                   ushort_t* __restrict__ sampb)
{
    __shared__ float wrec[16 * 168];
    __shared__ int   idxA[16 * 40];

    const int LD_[4]  = {4, 2, 1, 1};
    const int LH_[4]  = {48, 24, 12, 6};
    const int LW_[4]  = {48, 24, 12, 6};
    const int LS0_[4] = {0, 9216, 10368, 10512};

    int t   = threadIdx.x;
    int gl  = t >> 4;                   // local group 0..15
    int sub = t & 15;
    int h   = blockIdx.x;
    int r   = blockIdx.y * 16 + gl;
    bool valid = (r < M_ROWS);
    if (!valid) r = M_ROWS - 1;
    int b   = (r >= S_TOT) ? 1 : 0;
    int s   = r - b * S_TOT;

    float rx, ry, rz;
    {
        int j;
        if (s < 9216)       { j = s;         int qx = j % 48; int q2 = j / 48; int qy = q2 % 48; int qz = q2 / 48;
                              rx = (qx + 0.5f) * (1.f/48); ry = (qy + 0.5f) * (1.f/48); rz = (qz + 0.5f) * (1.f/4); }
        else if (s < 10368) { j = s - 9216;  int qx = j % 24; int q2 = j / 24; int qy = q2 % 24; int qz = q2 / 24;
                              rx = (qx + 0.5f) * (1.f/24); ry = (qy + 0.5f) * (1.f/24); rz = (qz + 0.5f) * (1.f/2); }
        else if (s < 10512) { j = s - 10368; int qx = j % 12; int qy = j / 12;
                              rx = (qx + 0.5f) * (1.f/12); ry = (qy + 0.5f) * (1.f/12); rz = 0.5f; }
        else                { j = s - 10512; int qx = j % 6;  int qy = j / 6;
                              rx = (qx + 0.5f) * (1.f/6);  ry = (qy + 0.5f) * (1.f/6);  rz = 0.5f; }
    }

    // ---- phase 1: one point per lane ----
    {
        int p = sub;
        float lg = bf2f(attnh[((size_t)h * M_ROWS + r) * 16 + p]);
        float mx = lg;
        mx = fmaxf(mx, __shfl_xor(mx, 1));
        mx = fmaxf(mx, __shfl_xor(mx, 2));
        mx = fmaxf(mx, __shfl_xor(mx, 4));
        mx = fmaxf(mx, __shfl_xor(mx, 8));
        float e = __expf(lg - mx);
        float sm = e;
        sm += __shfl_xor(sm, 1);
        sm += __shfl_xor(sm, 2);
        sm += __shfl_xor(sm, 4);
        sm += __shfl_xor(sm, 8);
        float aw = e / sm;

        int lvl = p >> 2;
        const int Dl = LD_[lvl], Hl = LH_[lvl], Wl = LW_[lvl];
        size_t base3 = ((size_t)h * M_ROWS + r) * 48 + p * 3;
        float cx = rx * Wl + bf2f(offh[base3 + 0]) - 0.5f;
        float cy = ry * Hl + bf2f(offh[base3 + 1]) - 0.5f;
        float cz = rz * Dl + bf2f(offh[base3 + 2]) - 0.5f;
        float xf = floorf(cx), yf = floorf(cy), zf = floorf(cz);
        float fx = cx - xf, fy = cy - yf, fz = cz - zf;
        int x0 = (int)xf, y0 = (int)yf, z0 = (int)zf;
        float wx0 = ((unsigned)x0       < (unsigned)Wl) ? 1.f - fx : 0.f;
        float wx1 = ((unsigned)(x0 + 1) < (unsigned)Wl) ? fx       : 0.f;
        float wy0 = ((unsigned)y0       < (unsigned)Hl) ? 1.f - fy : 0.f;
        float wy1 = ((unsigned)(y0 + 1) < (unsigned)Hl) ? fy       : 0.f;
        float wz0 = ((unsigned)z0       < (unsigned)Dl) ? (1.f - fz) * aw : 0.f;
        float wz1 = ((unsigned)(z0 + 1) < (unsigned)Dl) ? fz * aw       : 0.f;
        int xc = min(max(x0, -1), Wl - 1);
        int yc = min(max(y0, -1), Hl - 1);
        int zc = min(max(z0, -1), Dl - 1);
        int idx = LS0_[lvl] + (zc * Hl + yc) * Wl + xc;

        float* wp = &wrec[gl * 168 + p * 8];
        *(f32x4*)wp       = (f32x4){wz0 * wy0 * wx0, wz0 * wy0 * wx1,
                                    wz0 * wy1 * wx0, wz0 * wy1 * wx1};
        *(f32x4*)(wp + 4) = (f32x4){wz1 * wy0 * wx0, wz1 * wy0 * wx1,
                                    wz1 * wy1 * wx0, wz1 * wy1 * wx1};
        // pre-scaled to elements, pre-biased by the front guard: always > 0
        idxA[gl * 40 + p] = idx * HD_DIM + GUARD_USH;
    }
    __syncthreads();

    // ---- phase 2: corner cr = (dy,dx), channel octet q ----
    int q  = sub & 3;
    int cr = sub >> 2;
    int dy = cr >> 1, dx = cr & 1;
    // uniform SGPR base at guard start; per-lane u32 element offsets
    const ushort_t* base = valueb - GUARD_USH;
    unsigned laneofs = ((unsigned)(b * NH_DIM + h) * S_TOT) * HD_DIM + q * 8;
    f32x4 accA = (f32x4){0.f, 0.f, 0.f, 0.f};
    f32x4 accB = (f32x4){0.f, 0.f, 0.f, 0.f};

    #pragma unroll
    for (int p = 0; p < 16; ++p) {
        const int lvl = p >> 2;
        const int Wl = LW_[lvl];
        const int HW = LH_[lvl] * LW_[lvl];
        float w0 = wrec[gl * 168 + p * 8 + cr];
        float w1 = wrec[gl * 168 + p * 8 + 4 + cr];
        unsigned o0 = (unsigned)(idxA[gl * 40 + p] + (dy * Wl + dx) * HD_DIM) + laneofs;
        uint4 u0 = *(const uint4*)(base + (size_t)o0);
        uint4 u1 = *(const uint4*)(base + (size_t)(o0 + (unsigned)(HW * HD_DIM)));
        accA += w0 * up2(u0.x, u0.y);
        accB += w0 * up2(u0.z, u0.w);
        accA += w1 * up2(u1.x, u1.y);
        accB += w1 * up2(u1.z, u1.w);
    }

    accA.x += __shfl_xor(accA.x, 4); accA.y += __shfl_xor(accA.y, 4);
    accA.z += __shfl_xor(accA.z, 4); accA.w += __shfl_xor(accA.w, 4);
    accB.x += __shfl_xor(accB.x, 4); accB.y += __shfl_xor(accB.y, 4);
    accB.z += __shfl_xor(accB.z, 4); accB.w += __shfl_xor(accB.w, 4);
    accA.x += __shfl_xor(accA.x, 8); accA.y += __shfl_xor(accA.y, 8);
    accA.z += __shfl_xor(accA.z, 8); accA.w += __shfl_xor(accA.w, 8);
    accB.x += __shfl_xor(accB.x, 8); accB.y += __shfl_xor(accB.y, 8);
    accB.z += __shfl_xor(accB.z, 8); accB.w += __shfl_xor(accB.w, 8);

    if (cr == 0 && valid) {
        ushort4 o1, o2;
        o1.x = f2bf(accA.x); o1.y = f2bf(accA.y); o1.z = f2bf(accA.z); o1.w = f2bf(accA.w);
        o2.x = f2bf(accB.x); o2.y = f2bf(accB.y); o2.z = f2bf(accB.z); o2.w = f2bf(accB.w);
        ushort_t* op = sampb + (size_t)r * E_DIM + h * HD_DIM + q * 8;
        *(ushort4*)op       = o1;
        *(ushort4*)(op + 4) = o2;
    }
}

// ---------------------------------------------------------------------------
extern "C" void kernel_launch(void* const* d_in, const int* in_sizes, int n_in,
                              void* d_out, int out_size, void* d_ws, size_t ws_size,
                              hipStream_t stream)
{
    const float* f0     = (const float*)d_in[0];
    const float* p0     = (const float*)d_in[1];
    const float* f1     = (const float*)d_in[2];
    const float* p1     = (const float*)d_in[3];
    const float* f2     = (const float*)d_in[4];
    const float* p2     = (const float*)d_in[5];
    const float* f3     = (const float*)d_in[6];
    const float* p3     = (const float*)d_in[7];
    const float* lemb   = (const float*)d_in[8];
    const float* W_off  = (const float*)d_in[9];
    const float* b_off  = (const float*)d_in[10];
    const float* W_attn = (const float*)d_in[11];
    const float* b_attn = (const float*)d_in[12];
    const float* W_val  = (const float*)d_in[13];
    const float* b_val  = (const float*)d_in[14];
    const float* W_out  = (const float*)d_in[15];
    const float* b_out  = (const float*)d_in[16];
    const float* ln1_g  = (const float*)d_in[17];
    const float* ln1_b  = (const float*)d_in[18];
    const float* W_ff1  = (const float*)d_in[19];
    const float* b_ff1  = (const float*)d_in[20];
    const float* W_ff2  = (const float*)d_in[21];
    const float* b_ff2  = (const float*)d_in[22];
    const float* ln2_g  = (const float*)d_in[23];
    const float* ln2_b  = (const float*)d_in[24];

    float* x = (float*)d_out;
    char*  w = (char*)d_ws;

    // ws layout (bytes)
    ushort_t* posb   = (ushort_t*)(w + 0);                   // 10,813,440
    // value region: 256KB front guard | (B,NH,S,HD) bf16 | 128KB back guard
    ushort_t* valueb = (ushort_t*)(w + 21626880 + 262144);
    char*     region =            (w + 34525184);            // 43,253,760
    ushort_t* offh   = (ushort_t*)(region);                  // [NH][M][48] 16,220,160
    ushort_t* attnh  = (ushort_t*)(region + 16220160);       // [NH][M][16]  5,406,720
    ushort_t* sampb  = (ushort_t*)(region + 21626880);       // 10,813,440
    ushort_t* xb     = (ushort_t*)(w + 77778944);            // 10,813,440
    ushort_t* qb     = (ushort_t*)(w + 88592384);            // 10,813,440
    ushort_t* wb     = (ushort_t*)(w + 99405824);            //  9,437,184

    // Combined attention weight: per layer 768 rows x 256 K
    ushort_t* Wc_t = wb;              // [6][768][256]
    ushort_t* Wp_t = wb + 1179648;    // [6][256][256]
    ushort_t* W1_t = wb + 1572864;    // [6][1024][256]
    ushort_t* W2_t = wb + 3145728;    // [6][256][1024]

    dim3 blk(256);

    transpose_cvt_kernel<<<dim3(8, 8, 6),  blk, 0, stream>>>(W_val,  Wc_t, 256, 256,  196608, 0);
    transpose_cvt_kernel<<<dim3(12, 8, 6), blk, 0, stream>>>(W_off,  Wc_t, 256, 384,  196608, 256);
    transpose_cvt_kernel<<<dim3(4, 8, 6),  blk, 0, stream>>>(W_attn, Wc_t, 256, 128,  196608, 640);
    transpose_cvt_kernel<<<dim3(8, 8, 6),  blk, 0, stream>>>(W_out,  Wp_t, 256, 256,   65536, 0);
    transpose_cvt_kernel<<<dim3(32, 8, 6), blk, 0, stream>>>(W_ff1,  W1_t, 256, 1024, 262144, 0);
    transpose_cvt_kernel<<<dim3(8, 32, 6), blk, 0, stream>>>(W_ff2,  W2_t, 1024, 256, 262144, 0);

    // 331 j-tiles (288+36+5+2), 8 e-tiles, 2 batches
    assemble_kernel<<<dim3(331, 8, 2), blk, 0, stream>>>(
        f0, p0, f1, p1, f2, p2, f3, p3, lemb, x, posb, xb, qb);

    const int MT = M_PAD / 64;               // 330 (part1 grid.y)
    const int LT = M_PAD / 32;               // 660 (gemm_ln / ffn grids)
    const int SB = (M_ROWS + 15) / 16;       // 1319
    for (int l = 0; l < NLAYERS; ++l) {
        gemm_part1<<<dim3(3, MT), blk, 0, stream>>>(
            xb, qb, Wc_t + l * 196608,
            b_val + l * 256, b_off + l * 384, b_attn + l * 128,
            valueb, offh, attnh, M_ROWS);
        sample_kernel<<<dim3(NH_DIM, SB), blk, 0, stream>>>(valueb, offh, attnh, sampb);
        gemm_ln<<<LT, blk, 0, stream>>>(
            sampb, Wp_t + l * 65536, b_out + l * 256,
            x, xb, ln1_g + l * 256, ln1_b + l * 256, M_ROWS);
        ffn_kernel<<<LT, blk, 0, stream>>>(
            xb, W1_t + l * 262144, W2_t + l * 262144,
            b_ff1 + l * 1024, b_ff2 + l * 256,
            x, xb, qb, posb,
            ln2_g + l * 256, ln2_b + l * 256, M_ROWS);
    }
}